// Round 19
// baseline (498.808 us; speedup 1.0000x reference)
//
#include <hip/hip_runtime.h>
#include <hip/hip_bf16.h>
#include <cstdint>
#include <cstddef>

#define D 512
#define NHEAD 8
#define LMAX 512
#define NGIN 3

typedef unsigned short u16;
typedef unsigned long long u64;
typedef __attribute__((ext_vector_type(8))) short short8;
typedef __attribute__((ext_vector_type(8))) unsigned short ushort8;
typedef __attribute__((ext_vector_type(4))) unsigned short us4;
typedef __attribute__((ext_vector_type(4))) float f32x4;

static __device__ inline u16 f2bf(float f){
    union { float f; uint32_t u; } c; c.f = f;
    uint32_t r = (c.u + 0x7fffu + ((c.u >> 16) & 1u)) >> 16;
    return (u16)r;
}
static __device__ inline u16 tbf(float f){
    union { float f; uint32_t u; } c; c.f = f;
    return (u16)(c.u >> 16);
}
static __device__ inline float bf2f(u16 h){
    union { uint32_t u; float f; } c; c.u = ((uint32_t)h) << 16; return c.f;
}

#define GLOAD_LDS16(SRC, DST) \
    __builtin_amdgcn_global_load_lds( \
        (const __attribute__((address_space(1))) void*)(SRC), \
        (__attribute__((address_space(3))) void*)(DST), 16, 0, 0)

// ---------------- probe + memsets (one launch) ----------------
__global__ __launch_bounds__(256) void probe_mega(const int* __restrict__ ptr_raw,
        const unsigned char* __restrict__ mask_raw, int* __restrict__ flags,
        int* __restrict__ deg, int* __restrict__ cursor,
        float* __restrict__ sums, float* __restrict__ zbias, int N){
    int i = blockIdx.x*256 + threadIdx.x;
    if (i < N){ deg[i] = 0; cursor[i] = 0; }
    if (i < 1024){ sums[i] = 0.f; zbias[i] = 0.f; }
    if (blockIdx.x == 0 && threadIdx.x == 0){
        flags[0] = (ptr_raw[1] == 0) ? 1 : 0;
        int cntOdd = 0, cnt4 = 0;
        for (int k = 1; k < 2048; k += 2) cntOdd += (mask_raw[k] != 0);
        for (int k = 4; k < 2048; k += 8) cnt4   += (mask_raw[k] != 0);
        flags[1] = (cntOdd > 64) ? 1 : ((cnt4 > 16) ? 4 : 8);
    }
}

// ---------------- mega prologue: z-roles ----------------
__global__ __launch_bounds__(256) void mega_prologue(
        const float* __restrict__ v_w, const float* __restrict__ gin_w1,
        const float* __restrict__ gin_w2, const float* __restrict__ se_w,
        const float* __restrict__ out_w, const float* __restrict__ qk_w,
        u16* __restrict__ wtsh, u16* __restrict__ wtsl,
        const unsigned char* __restrict__ mask_raw, u64* __restrict__ mbits,
        const float* __restrict__ x, u16* __restrict__ Xh, u16* __restrict__ Xl,
        u16* __restrict__ sewh, u16* __restrict__ sewl,
        const int* __restrict__ ptr_raw, int* __restrict__ ptr32,
        const int* __restrict__ ei_raw, int* __restrict__ deg,
        const int* __restrict__ flags,
        int Nnodes, int E, int B, int Mn64){
    int z = blockIdx.z;
    int bid = blockIdx.y*32 + blockIdx.x;
    int tid = threadIdx.x;
    if (z <= 9){
        int Nout = (z == 9) ? 1024 : 512;
        if (z < 9 && blockIdx.x >= 16) return;
        const size_t SLOT = 262144;
        const float* W; int slot;
        switch (z){
            case 0: W = v_w; slot = 0; break;
            case 1: W = gin_w1;          slot = 1; break;
            case 2: W = gin_w2;          slot = 2; break;
            case 3: W = gin_w1 + 262144; slot = 3; break;
            case 4: W = gin_w2 + 262144; slot = 4; break;
            case 5: W = gin_w1 + 524288; slot = 5; break;
            case 6: W = gin_w2 + 524288; slot = 6; break;
            case 7: W = se_w;  slot = 7; break;
            case 8: W = out_w; slot = 10; break;
            default: W = qk_w; slot = 8; break;
        }
        u16* Wh = wtsh + SLOT*slot;
        u16* Wl = wtsl + SLOT*slot;
        __shared__ float T[32][33];
        int nb = blockIdx.x*32, kb = blockIdx.y*32;
        int ln = tid & 31, lk = tid >> 5;
        #pragma unroll
        for (int i = 0; i < 4; i++)
            T[lk + 8*i][ln] = W[(size_t)(kb + lk + 8*i)*Nout + nb + ln];
        __syncthreads();
        #pragma unroll
        for (int i = 0; i < 4; i++){
            float val = T[ln][lk + 8*i];
            u16 h = tbf(val);
            size_t idx = (size_t)(nb + lk + 8*i)*512 + kb + ln;
            Wh[idx] = h;
            Wl[idx] = tbf(val - bf2f(h));
        }
    } else if (z == 10){
        int idx = bid*256 + tid;
        if (idx >= Mn64) return;
        int w = flags[1];
        size_t ebase = (size_t)(idx >> 3) * 512 + (size_t)(idx & 7) * 64;
        u64 bits = 0;
        if (w == 1){
            const u64* p8 = (const u64*)(mask_raw + ebase);
            #pragma unroll
            for (int g = 0; g < 8; g++){
                u64 v = p8[g];
                #pragma unroll
                for (int by = 0; by < 8; by++)
                    if ((v >> (by*8)) & 0xffull) bits |= 1ull << (g*8 + by);
            }
        } else {
            for (int j = 0; j < 64; j++)
                if (mask_raw[(ebase + j) * (size_t)w]) bits |= 1ull << j;
        }
        mbits[idx] = bits;
    } else if (z == 11){
        int total4 = Nnodes*D/4;
        for (int i = bid*256 + tid; i < total4; i += 131072){
            float4 v = *(const float4*)(x + (size_t)i*4);
            float fv[4] = {v.x, v.y, v.z, v.w};
            us4 h4, l4;
            #pragma unroll
            for (int j = 0; j < 4; j++){
                u16 hh = tbf(fv[j]);
                h4[j] = hh;
                l4[j] = tbf(fv[j] - bf2f(hh));
            }
            *(us4*)(Xh + (size_t)i*4) = h4;
            *(us4*)(Xl + (size_t)i*4) = l4;
        }
    } else if (z == 12){
        int i = bid*256 + tid;
        if (i >= D*D/4) return;
        float4 v = *(const float4*)(se_w + (size_t)i*4);
        float fv[4] = {v.x, v.y, v.z, v.w};
        us4 h4, l4;
        #pragma unroll
        for (int j = 0; j < 4; j++){
            u16 hh = tbf(fv[j]);
            h4[j] = hh;
            l4[j] = tbf(fv[j] - bf2f(hh));
        }
        *(us4*)(sewh + (size_t)i*4) = h4;
        *(us4*)(sewl + (size_t)i*4) = l4;
    } else if (z == 13){
        if (bid == 0 && tid <= B)
            ptr32[tid] = flags[0] ? ptr_raw[2*tid] : ptr_raw[tid];
    } else {
        int e = bid*256 + tid;
        if (e < E){
            int d = flags[0] ? ei_raw[2*(E + e)] : ei_raw[E + e];
            if ((unsigned)d < (unsigned)Nnodes) atomicAdd(&deg[d], 1);
        }
    }
}

// ---------------- parallel scan: A (local) / B (bases); base-add folded into consumers ----------------
__global__ __launch_bounds__(1024) void scanA(const int* __restrict__ deg,
        int* __restrict__ offs, int* __restrict__ totals, int n){
    __shared__ int wsum[16];
    int ch = blockIdx.x;
    int tid = threadIdx.x, lane = tid & 63, wv = tid >> 6;
    int i = ch*1024 + tid;
    int val = (i < n) ? deg[i] : 0;
    int s = val;
    #pragma unroll
    for (int off = 1; off < 64; off <<= 1){
        int t = __shfl_up(s, off);
        if (lane >= off) s += t;
    }
    if (lane == 63) wsum[wv] = s;
    __syncthreads();
    if (wv == 0){
        int t = (lane < 16) ? wsum[lane] : 0;
        #pragma unroll
        for (int off = 1; off < 16; off <<= 1){
            int u = __shfl_up(t, off);
            if (lane >= off) t += u;
        }
        if (lane < 16) wsum[lane] = t;
    }
    __syncthreads();
    int wbase = wv ? wsum[wv-1] : 0;
    if (i < n) offs[i+1] = wbase + s;
    if (tid == 1023) totals[ch] = wsum[15];
    if (ch == 0 && tid == 0) offs[0] = 0;
}

__global__ void scanB(int* __restrict__ totals, int nch){
    int lane = threadIdx.x;
    int v = (lane < nch) ? totals[lane] : 0;
    int s = v;
    #pragma unroll
    for (int off = 1; off < 64; off <<= 1){
        int t = __shfl_up(s, off);
        if (lane >= off) s += t;
    }
    if (lane < nch) totals[lane] = s - v;   // exclusive chunk base
}

// offs_final[i] = offs[i] + (i>=1 ? totals[(i-1)>>10] : 0)
__global__ void fill_kernel(const int* __restrict__ ei_raw, const int* __restrict__ offs,
                            const int* __restrict__ totals,
                            int* __restrict__ cursor, int* __restrict__ in_src,
                            const int* __restrict__ flags, int E, int N){
    int e = blockIdx.x*256 + threadIdx.x;
    if (e < E){
        int d = flags[0] ? ei_raw[2*(E + e)] : ei_raw[E + e];
        if ((unsigned)d < (unsigned)N){
            int slot = atomicAdd(&cursor[d], 1);
            int start = offs[d] + (d ? totals[(d-1) >> 10] : 0);
            in_src[start + slot] = flags[0] ? ei_raw[2*e] : ei_raw[e];
        }
    }
}

// ---------------- gather ----------------
__global__ __launch_bounds__(256) void gather_kernel(const u16* __restrict__ hh,
        const u16* __restrict__ hl,
        const int* __restrict__ offs, const int* __restrict__ totals,
        const int* __restrict__ in_src,
        u16* __restrict__ oh, u16* __restrict__ ol, int N){
    int node = blockIdx.x*2 + (threadIdx.x >> 7);
    if (node >= N) return;
    int t = threadIdx.x & 127;
    size_t rb = (size_t)node*D + t*4;
    us4 vh = *(const us4*)(hh + rb);
    us4 vl = *(const us4*)(hl + rb);
    float a[4];
    #pragma unroll
    for (int j = 0; j < 4; j++) a[j] = bf2f(vh[j]) + bf2f(vl[j]);
    int s = offs[node] + (node ? totals[(node-1) >> 10] : 0);
    int e = offs[node+1] + totals[node >> 10];
    for (int i = s; i < e; i++){
        size_t sb = (size_t)in_src[i]*D + t*4;
        us4 nh = *(const us4*)(hh + sb);
        us4 nl = *(const us4*)(hl + sb);
        #pragma unroll
        for (int j = 0; j < 4; j++) a[j] += bf2f(nh[j]) + bf2f(nl[j]);
    }
    us4 h4, l4;
    #pragma unroll
    for (int j = 0; j < 4; j++){
        u16 hh2 = tbf(a[j]);
        h4[j] = hh2;
        l4[j] = tbf(a[j] - bf2f(hh2));
    }
    *(us4*)(oh + rb) = h4;
    *(us4*)(ol + rb) = l4;
}

// ---------------- fold mega ----------------
__global__ __launch_bounds__(256) void fold_mega(const float* __restrict__ M1,
        const float* __restrict__ sums, const float* __restrict__ gamma,
        const float* __restrict__ beta,
        const float* __restrict__ se_b, const float* __restrict__ qk_w,
        const float* __restrict__ qk_b,
        u16* __restrict__ Wh, u16* __restrict__ Wl, float* __restrict__ bbig, int n){
    float inv_n = 1.f / (float)n;
    if (blockIdx.z == 0){
        __shared__ float T[32][33];
        int nb = blockIdx.x*32, kb = blockIdx.y*32;
        int ln = threadIdx.x & 31, lk = threadIdx.x >> 5;
        #pragma unroll
        for (int i = 0; i < 4; i++){
            int k = kb + lk + 8*i;
            float mean = sums[k] * inv_n;
            float var = sums[512+k] * inv_n - mean*mean;
            float scale = rsqrtf(var + 1e-5f) * gamma[k];
            T[lk + 8*i][ln] = M1[(size_t)k*1024 + nb + ln] * scale;
        }
        __syncthreads();
        #pragma unroll
        for (int i = 0; i < 4; i++){
            float val = T[ln][lk + 8*i];
            u16 h = tbf(val);
            size_t idx = (size_t)(nb + lk + 8*i)*512 + kb + ln;
            Wh[idx] = h;
            Wl[idx] = tbf(val - bf2f(h));
        }
    } else {
        int wv = threadIdx.x >> 6, lane = threadIdx.x & 63;
        if (wv >= 2) return;
        int nidx = (blockIdx.y*32 + blockIdx.x)*2 + wv;
        float acc = 0.f;
        for (int k = lane; k < 512; k += 64){
            float mean = sums[k] * inv_n;
            float var = sums[512+k] * inv_n - mean*mean;
            float scale = rsqrtf(var + 1e-5f) * gamma[k];
            float shift = beta[k] - mean*scale;
            acc += shift*M1[(size_t)k*1024 + nidx] + se_b[k]*qk_w[(size_t)k*1024 + nidx];
        }
        #pragma unroll
        for (int off = 32; off > 0; off >>= 1) acc += __shfl_xor(acc, off);
        if (lane == 0) bbig[nidx] = acc + qk_b[nidx];
    }
}

// ---------------- shared GEMM body: 128x64 tile, 256 thr, 48KB LDS arena ----------------
template<int ACT, int EPI, int TERMS, int STATS>
__device__ __forceinline__ void gemm_body(char* ldsbase,
        const u16* __restrict__ Ahg, const u16* __restrict__ Alg,
        const u16* __restrict__ Wth, const u16* __restrict__ Wtl,
        const float* __restrict__ bias,
        void* __restrict__ C0, void* __restrict__ C1,
        float* __restrict__ stat_sums, int K, int Nout, int rowBase, int colBase){
    u16 (*Ah)[64] = (u16(*)[64])(ldsbase);
    u16 (*Al)[64] = (u16(*)[64])(ldsbase + 16384);
    u16 (*Bh)[64] = (u16(*)[64])(ldsbase + 32768);
    u16 (*Bl)[64] = (u16(*)[64])(ldsbase + 40960);
    int tid = threadIdx.x;
    int w = tid >> 6, l = tid & 63, lg = l >> 4, lm = l & 15;
    int wr = w >> 1, wc = w & 1;
    f32x4 acc[4][2] = {};
    const u16* Ahp = Ahg + (size_t)rowBase*K;
    const u16* Alp = (TERMS == 3) ? Alg + (size_t)rowBase*K : nullptr;
    const u16* Wph = Wth + (size_t)colBase*K;
    const u16* Wpl = Wtl + (size_t)colBase*K;
    int srowA[4], scolA[4], srowB[2], scolB[2];
    #pragma unroll
    for (int c = 0; c < 4; c++){
        int slot = c*256 + tid;
        srowA[c] = slot >> 3;
        scolA[c] = ((slot & 7) ^ (srowA[c] & 7)) * 8;
    }
    #pragma unroll
    for (int c = 0; c < 2; c++){
        int slot = c*256 + tid;
        srowB[c] = slot >> 3;
        scolB[c] = ((slot & 7) ^ (srowB[c] & 7)) * 8;
    }
    for (int k0 = 0; k0 < K; k0 += 64){
        #pragma unroll
        for (int c = 0; c < 4; c++){
            int slot = c*256 + tid;
            size_t so = (size_t)srowA[c]*K + k0 + scolA[c];
            GLOAD_LDS16(Ahp + so, &Ah[0][0] + slot*8);
            if (TERMS == 3) GLOAD_LDS16(Alp + so, &Al[0][0] + slot*8);
        }
        #pragma unroll
        for (int c = 0; c < 2; c++){
            int slot = c*256 + tid;
            size_t so = (size_t)srowB[c]*K + k0 + scolB[c];
            GLOAD_LDS16(Wph + so, &Bh[0][0] + slot*8);
            GLOAD_LDS16(Wpl + so, &Bl[0][0] + slot*8);
        }
        __syncthreads();
        #pragma unroll
        for (int ks = 0; ks < 2; ks++){
            int scg = ((ks*4 + lg) ^ (lm & 7)) * 8;
            short8 ah[4], al[4], bh[2], bl[2];
            #pragma unroll
            for (int mf = 0; mf < 4; mf++){
                ah[mf] = *(const short8*)&Ah[wr*64 + mf*16 + lm][scg];
                if (TERMS == 3) al[mf] = *(const short8*)&Al[wr*64 + mf*16 + lm][scg];
            }
            #pragma unroll
            for (int nf = 0; nf < 2; nf++){
                bh[nf] = *(const short8*)&Bh[wc*32 + nf*16 + lm][scg];
                bl[nf] = *(const short8*)&Bl[wc*32 + nf*16 + lm][scg];
            }
            __builtin_amdgcn_s_setprio(1);
            #pragma unroll
            for (int mf = 0; mf < 4; mf++)
                #pragma unroll
                for (int nf = 0; nf < 2; nf++){
                    acc[mf][nf] = __builtin_amdgcn_mfma_f32_16x16x32_bf16(ah[mf], bh[nf], acc[mf][nf], 0, 0, 0);
                    if (TERMS == 3)
                        acc[mf][nf] = __builtin_amdgcn_mfma_f32_16x16x32_bf16(al[mf], bh[nf], acc[mf][nf], 0, 0, 0);
                    acc[mf][nf] = __builtin_amdgcn_mfma_f32_16x16x32_bf16(ah[mf], bl[nf], acc[mf][nf], 0, 0, 0);
                }
            __builtin_amdgcn_s_setprio(0);
        }
        __syncthreads();
    }
    #pragma unroll
    for (int nf = 0; nf < 2; nf++){
        int col = colBase + wc*32 + nf*16 + lm;
        float bv = bias[col];
        float ssum = 0.f, ssq = 0.f;
        #pragma unroll
        for (int mf = 0; mf < 4; mf++){
            int row = rowBase + wr*64 + mf*16 + lg*4;
            #pragma unroll
            for (int j = 0; j < 4; j++){
                float o = acc[mf][nf][j] + bv;
                if (ACT) o = fmaxf(o, 0.f);
                if (STATS){ ssum += o; ssq += o*o; }
                size_t idx = (size_t)(row + j)*Nout + col;
                if (EPI == 0){
                    ((float*)C0)[idx] = o;
                } else if (EPI == 1){
                    u16 hh = tbf(o);
                    ((u16*)C0)[idx] = hh;
                    ((u16*)C1)[idx] = tbf(o - bf2f(hh));
                } else {
                    ((u16*)C0)[idx] = f2bf(o);
                }
            }
        }
        if (STATS){
            ssum += __shfl_xor(ssum, 16); ssum += __shfl_xor(ssum, 32);
            ssq  += __shfl_xor(ssq, 16);  ssq  += __shfl_xor(ssq, 32);
            if (lg == 0){
                atomicAdd(&stat_sums[col], ssum);
                atomicAdd(&stat_sums[512 + col], ssq);
            }
        }
    }
}

static __device__ inline void xcd_tile(int gx, int gy, int& rowBase, int& colBase){
    int nwg = gx * gy;
    int orig = blockIdx.x + gx*blockIdx.y;
    int q8 = nwg >> 3, r8 = nwg & 7;
    int xcd = orig & 7, pos = orig >> 3;
    int wg = (xcd < r8 ? xcd*(q8+1) : r8*(q8+1) + (xcd - r8)*q8) + pos;
    rowBase = (wg / gx) * 128;
    colBase = (wg % gx) * 64;
}

// standalone GEMM kernel
template<int ACT, int EPI, int TERMS, int STATS>
__global__ __launch_bounds__(256) void gemm_ps(const u16* __restrict__ Ahg,
        const u16* __restrict__ Alg,
        const u16* __restrict__ Wth, const u16* __restrict__ Wtl,
        const float* __restrict__ bias,
        void* __restrict__ C0, void* __restrict__ C1,
        float* __restrict__ stat_sums, int K, int Nout){
    __shared__ __align__(16) char lds[49152];
    int rowBase, colBase;
    xcd_tile(gridDim.x, gridDim.y, rowBase, colBase);
    gemm_body<ACT,EPI,TERMS,STATS>(lds, Ahg, Alg, Wth, Wtl, bias, C0, C1, stat_sums, K, Nout, rowBase, colBase);
}

// triple-merged launch: z=0 GIN-1a, z=1 v GEMM, z=2 M1
__global__ __launch_bounds__(256) void triple_gemm(
        const u16* __restrict__ Gh, const u16* __restrict__ Gl,
        const u16* __restrict__ w1h, const u16* __restrict__ w1l,
        const float* __restrict__ b1, u16* __restrict__ Th, u16* __restrict__ Tl,
        const u16* __restrict__ Xh,
        const u16* __restrict__ wvh, const u16* __restrict__ wvl,
        const float* __restrict__ vb, u16* __restrict__ vbf,
        const u16* __restrict__ sewh, const u16* __restrict__ sewl,
        const u16* __restrict__ wqkh, const u16* __restrict__ wqkl,
        const float* __restrict__ zbias, float* __restrict__ M1){
    __shared__ __align__(16) char lds[49152];
    int z = blockIdx.z;
    if (z <= 1){
        int rowBase, colBase;
        xcd_tile(gridDim.x, gridDim.y, rowBase, colBase);
        if (z == 0)
            gemm_body<1,1,3,0>(lds, Gh, Gl, w1h, w1l, b1, Th, Tl, nullptr, 512, 512, rowBase, colBase);
        else
            gemm_body<0,2,2,0>(lds, Xh, nullptr, wvh, wvl, vb, vbf, nullptr, nullptr, 512, 512, rowBase, colBase);
    } else {
        int orig = blockIdx.x + gridDim.x*blockIdx.y;
        if (orig >= 64) return;
        int rowBase = (orig >> 4) * 128, colBase = (orig & 15) * 64;
        gemm_body<0,0,3,0>(lds, sewh, sewl, wqkh, wqkl, zbias, M1, nullptr, nullptr, 512, 1024, rowBase, colBase);
    }
}

// ---------------- MFMA ragged masked flash attention, 128-row q-blocks ----------------
// XCD-swizzled block relabel: q-block siblings of one (b,h) land co-XCD for K/V L2 reuse.
#define ATS 72
__global__ __launch_bounds__(512) void attn_mfma_kernel(const u16* __restrict__ qkH,
        const u16* __restrict__ qkL, const u16* __restrict__ vbf,
        const u64* __restrict__ maskbits,
        const int* __restrict__ ptr, u16* __restrict__ oh, int N){
    __shared__ u16 Kh[64][ATS];
    __shared__ u16 Kl[64][ATS];
    __shared__ u16 Vt[64][ATS];
    __shared__ u16 Pl[8][16][ATS];
    // grid (4, 8, 32) = 1024 blocks; orig%8 = XCD slot. nid = xcd*128 + pos, decode q-fastest.
    int orig = blockIdx.x + 4*blockIdx.y + 32*blockIdx.z;
    int xcd = orig & 7, pos = orig >> 3;
    int nid = xcd*128 + pos;
    int q0 = (nid & 3) * 128;
    int h  = (nid >> 2) & 7;
    int b  = nid >> 5;
    int base = ptr[b], size = ptr[b+1] - base;
    if (q0 >= size) return;
    int tid = threadIdx.x, w = tid >> 6, l = tid & 63;
    int lg = l >> 4, lm = l & 15;
    short8 qh[2], ql[2];
    {
        int qrow = q0 + w*16 + lm;
        int qr = (qrow < size) ? qrow : 0;
        const u16* qph = qkH + (size_t)(base + qr)*1024 + 512 + h*64;
        const u16* qpl = qkL + (size_t)(base + qr)*1024 + 512 + h*64;
        #pragma unroll
        for (int ks = 0; ks < 2; ks++){
            short8 th = *(const short8*)(qph + ks*32 + lg*8);
            short8 tl = *(const short8*)(qpl + ks*32 + lg*8);
            if (qrow >= size){ th = short8{0,0,0,0,0,0,0,0}; tl = short8{0,0,0,0,0,0,0,0}; }
            qh[ks] = th; ql[ks] = tl;
        }
    }
    f32x4 acco[4] = {};
    float mrow[4], lrow[4];
    #pragma unroll
    for (int j = 0; j < 4; j++){ mrow[j] = -INFINITY; lrow[j] = 0.f; }
    int nt = (size + 63) >> 6;
    for (int t = 0; t < nt; t++){
        int j0 = t*64;
        __syncthreads();
        {
            int jj = tid & 63, db = (tid >> 6)*8;
            int key = j0 + jj;
            bool ok = key < size;
            size_t node = (size_t)(base + (ok ? key : 0));
            const u16* khp = qkH + node*1024 + h*64 + db;
            const u16* klp = qkL + node*1024 + h*64 + db;
            const u16* vp  = vbf + node*512  + h*64 + db;
            ushort8 z = {0,0,0,0,0,0,0,0};
            ushort8 kh0 = ok ? *(const ushort8*)(khp) : z;
            ushort8 kl0 = ok ? *(const ushort8*)(klp) : z;
            ushort8 v0  = ok ? *(const ushort8*)(vp)  : z;
            *(ushort8*)&Kh[jj][db] = kh0;
            *(ushort8*)&Kl[jj][db] = kl0;
            #pragma unroll
            for (int i = 0; i < 8; i++) Vt[db + i][jj] = v0[i];
        }
        __syncthreads();
        f32x4 sc[4] = {};
        __builtin_amdgcn_s_setprio(1);
        #pragma unroll
        for (int nf = 0; nf < 4; nf++)
            #pragma unroll
            for (int ks = 0; ks < 2; ks++){
                short8 kh = *(const short8*)&Kh[nf*16 + lm][ks*32 + lg*8];
                short8 kl = *(const short8*)&Kl[nf*16 + lm][ks*32 + lg*8];
                sc[nf] = __builtin_amdgcn_mfma_f32_16x16x32_bf16(qh[ks], kh, sc[nf], 0, 0, 0);
                sc[nf] = __builtin_amdgcn_mfma_f32_16x16x32_bf16(ql[ks], kh, sc[nf], 0, 0, 0);
                sc[nf] = __builtin_amdgcn_mfma_f32_16x16x32_bf16(qh[ks], kl, sc[nf], 0, 0, 0);
            }
        __builtin_amdgcn_s_setprio(0);
        u64 mb[4];
        #pragma unroll
        for (int j = 0; j < 4; j++)
            mb[j] = maskbits[((size_t)b*LMAX + (q0 + w*16 + lg*4 + j))*8 + t];
        float mx[4], alpha[4];
        #pragma unroll
        for (int j = 0; j < 4; j++){
            float s0 = -INFINITY;
            #pragma unroll
            for (int nf = 0; nf < 4; nf++){
                int key = j0 + nf*16 + lm;
                float s = sc[nf][j] * 0.125f;
                bool msk = (key >= size) || ((mb[j] >> (nf*16 + lm)) & 1);
                s = msk ? -INFINITY : s;
                sc[nf][j] = s;
                s0 = fmaxf(s0, s);
            }
            #pragma unroll
            for (int off = 1; off < 16; off <<= 1) s0 = fmaxf(s0, __shfl_xor(s0, off));
            mx[j] = s0;
        }
        #pragma unroll
        for (int j = 0; j < 4; j++){
            if (mx[j] == -INFINITY){ alpha[j] = 1.f; }
            else {
                float mn = fmaxf(mrow[j], mx[j]);
                alpha[j] = __expf(mrow[j] - mn);
                mrow[j] = mn;
            }
        }
        float ps[4] = {0.f, 0.f, 0.f, 0.f};
        #pragma unroll
        for (int nf = 0; nf < 4; nf++)
            #pragma unroll
            for (int j = 0; j < 4; j++){
                float p = (mx[j] == -INFINITY) ? 0.f : __expf(sc[nf][j] - mrow[j]);
                ps[j] += p;
                Pl[w][lg*4 + j][nf*16 + lm] = tbf(p);
            }
        #pragma unroll
        for (int j = 0; j < 4; j++){
            float s = ps[j];
            #pragma unroll
            for (int off = 1; off < 16; off <<= 1) s += __shfl_xor(s, off);
            lrow[j] = lrow[j]*alpha[j] + s;
        }
        #pragma unroll
        for (int df = 0; df < 4; df++)
            #pragma unroll
            for (int j = 0; j < 4; j++) acco[df][j] *= alpha[j];
        __builtin_amdgcn_s_setprio(1);
        #pragma unroll
        for (int ks = 0; ks < 2; ks++){
            short8 pf = *(const short8*)&Pl[w][lm][ks*32 + lg*8];
            #pragma unroll
            for (int df = 0; df < 4; df++){
                short8 vf = *(const short8*)&Vt[df*16 + lm][ks*32 + lg*8];
                acco[df] = __builtin_amdgcn_mfma_f32_16x16x32_bf16(pf, vf, acco[df], 0, 0, 0);
            }
        }
        __builtin_amdgcn_s_setprio(0);
    }
    #pragma unroll
    for (int j = 0; j < 4; j++){
        int r = q0 + w*16 + lg*4 + j;
        if (r < size){
            float inv = 1.f / lrow[j];
            #pragma unroll
            for (int df = 0; df < 4; df++){
                float o = acco[df][j] * inv;
                oh[(size_t)(base + r)*D + h*64 + df*16 + lm] = f2bf(o);
            }
        }
    }
}

extern "C" void kernel_launch(void* const* d_in, const int* in_sizes, int n_in,
                              void* d_out, int out_size, void* d_ws, size_t ws_size,
                              hipStream_t stream){
    const float* x        = (const float*)d_in[0];
    const int*   ei_raw   = (const int*)d_in[1];
    const unsigned char* mask_raw = (const unsigned char*)d_in[2];
    const int*   ptr_raw  = (const int*)d_in[3];
    const float* gin_w1   = (const float*)d_in[4];
    const float* gin_b1   = (const float*)d_in[5];
    const float* gin_w2   = (const float*)d_in[6];
    const float* gin_b2   = (const float*)d_in[7];
    const float* bn_gamma = (const float*)d_in[8];
    const float* bn_beta  = (const float*)d_in[9];
    const float* se_w     = (const float*)d_in[10];
    const float* se_b     = (const float*)d_in[11];
    const float* qk_w     = (const float*)d_in[12];
    const float* qk_b     = (const float*)d_in[13];
    const float* v_w      = (const float*)d_in[14];
    const float* v_b      = (const float*)d_in[15];
    const float* out_w    = (const float*)d_in[16];
    const float* out_b    = (const float*)d_in[17];

    const int N  = in_sizes[0] / D;       // 12160
    const int E  = in_sizes[1] / 2;       // 97280
    const int B  = in_sizes[3] - 1;       // 32
    const int Mn = in_sizes[2];           // B*512*512

    char* ws = (char*)d_ws;
    char* p = ws;
    auto alloc = [&](size_t bytes) -> char* {
        char* q = p; p += (bytes + 255) & ~(size_t)255; return q;
    };
    size_t PLANE = (size_t)N * D * sizeof(u16);
    u16* pairX = (u16*)alloc(2*PLANE);
    u16* pairG = (u16*)alloc(2*PLANE);
    u16* pairT = (u16*)alloc(2*PLANE);
    u16* pairH = (u16*)alloc(2*PLANE);
    u16* v_bf  = (u16*)alloc(PLANE);
    u16* Xh = pairX, *Xl = pairX + (size_t)N*D;
    u16* Gh = pairG, *Gl = pairG + (size_t)N*D;
    u16* Th = pairT, *Tl = pairT + (size_t)N*D;
    u16* Hh = pairH, *Hl = pairH + (size_t)N*D;
    float* sums   = (float*)alloc(1024*sizeof(float));
    int*   flags  = (int*)alloc(16*sizeof(int));
    int*   deg    = (int*)alloc((size_t)N*sizeof(int));
    int*   offs   = (int*)alloc((size_t)(N+1)*sizeof(int));
    int*   cursor = (int*)alloc((size_t)N*sizeof(int));
    int*   in_src = (int*)alloc((size_t)E*sizeof(int));
    int*   ptr32  = (int*)alloc(64*sizeof(int));
    int*   totals = (int*)alloc(64*sizeof(int));
    u64*   mbits  = (u64*)alloc((size_t)(Mn/64)*sizeof(u64));
    u16*   wtsh   = (u16*)alloc((size_t)2883584*sizeof(u16));
    u16*   wtsl   = (u16*)alloc((size_t)2883584*sizeof(u16));
    u16*   sewh   = (u16*)alloc((size_t)D*D*sizeof(u16));
    u16*   sewl   = (u16*)alloc((size_t)D*D*sizeof(u16));
    float* M1     = (float*)alloc((size_t)D*1024*sizeof(float));
    u16*   wbig_h = (u16*)alloc((size_t)1024*D*sizeof(u16));
    u16*   wbig_l = (u16*)alloc((size_t)1024*D*sizeof(u16));
    float* bbig   = (float*)alloc(1024*sizeof(float));
    float* zbias  = (float*)alloc(1024*sizeof(float));
    const size_t SLOT = 262144;
    u16 *wh_v = wtsh, *wl_v = wtsl;
    u16 *wh_g[6], *wl_g[6];
    for (int i = 0; i < 6; i++){ wh_g[i] = wtsh + SLOT*(1+i); wl_g[i] = wtsl + SLOT*(1+i); }
    u16 *wh_qk  = wtsh + SLOT*8,  *wl_qk  = wtsl + SLOT*8;
    u16 *wh_out = wtsh + SLOT*10, *wl_out = wtsl + SLOT*10;

    // --- probe + memsets, mega prologue ---
    probe_mega<<<(N + 255)/256, 256, 0, stream>>>(ptr_raw, mask_raw, flags,
        deg, cursor, sums, zbias, N);
    mega_prologue<<<dim3(32,16,15), 256, 0, stream>>>(
        v_w, gin_w1, gin_w2, se_w, out_w, qk_w, wtsh, wtsl,
        mask_raw, mbits, x, Xh, Xl, sewh, sewl,
        ptr_raw, ptr32, ei_raw, deg, flags, N, E, B, Mn/64);
    int nch = (N + 1023)/1024;
    scanA<<<nch, 1024, 0, stream>>>(deg, offs, totals, N);
    scanB<<<1, 64, 0, stream>>>(totals, nch);
    fill_kernel<<<(E+255)/256, 256, 0, stream>>>(ei_raw, offs, totals, cursor, in_src, flags, E, N);

    dim3 g512(8, N/128), g1024(16, N/128);

    // GIN layer 0: gather, then triple launch {GIN-1a, v GEMM, M1}
    gather_kernel<<<(N+1)/2, 256, 0, stream>>>(Xh, Xl, offs, totals, in_src, Gh, Gl, N);
    triple_gemm<<<dim3(8, N/128, 3), 256, 0, stream>>>(
        Gh, Gl, wh_g[0], wl_g[0], gin_b1, Th, Tl,
        Xh, wh_v, wl_v, v_b, v_bf,
        sewh, sewl, wh_qk, wl_qk, zbias, M1);
    gemm_ps<1,1,3,0><<<g512, 256, 0, stream>>>(Th, Tl, wh_g[1], wl_g[1], gin_b2, Hh, Hl, nullptr, D, D);

    // GIN layers 1..2
    for (int i = 1; i < NGIN; i++){
        gather_kernel<<<(N+1)/2, 256, 0, stream>>>(Hh, Hl, offs, totals, in_src, Gh, Gl, N);
        gemm_ps<1,1,3,0><<<g512, 256, 0, stream>>>(Gh, Gl, wh_g[2*i], wl_g[2*i], gin_b1 + (size_t)i*D, Th, Tl, nullptr, D, D);
        if (i == NGIN - 1)
            gemm_ps<1,1,3,1><<<g512, 256, 0, stream>>>(Th, Tl, wh_g[2*i+1], wl_g[2*i+1], gin_b2 + (size_t)i*D, Hh, Hl, sums, D, D);
        else
            gemm_ps<1,1,3,0><<<g512, 256, 0, stream>>>(Th, Tl, wh_g[2*i+1], wl_g[2*i+1], gin_b2 + (size_t)i*D, Hh, Hl, nullptr, D, D);
    }

    // fold BN + se into qk weight
    fold_mega<<<dim3(32,16,2), 256, 0, stream>>>(M1, sums, bn_gamma, bn_beta,
        se_b, qk_w, qk_b, wbig_h, wbig_l, bbig, N);

    // qk = gin_out @ Wbig + bbig -> hi plane = pairX (N x 1024), lo plane = pairG
    gemm_ps<0,1,3,0><<<g1024, 256, 0, stream>>>(Hh, Hl, wbig_h, wbig_l, bbig, pairX, pairG, nullptr, D, 2*D);

    // attention (XCD-swizzled): split qk + bf16 v -> plain bf16 output in Th
    attn_mfma_kernel<<<dim3(LMAX/128, NHEAD, B), 512, 0, stream>>>(pairX, pairG, v_bf, mbits, ptr32, Th, N);

    // out = attn_out @ out_w + out_b -> f32 d_out (2-term)
    gemm_ps<0,0,2,0><<<g512, 256, 0, stream>>>(Th, nullptr, wh_out, wl_out, out_b, (float*)d_out, nullptr, nullptr, D, D);
}

// Round 20
// 484.483 us; speedup vs baseline: 1.0296x; 1.0296x over previous
//
#include <hip/hip_runtime.h>
#include <hip/hip_bf16.h>
#include <cstdint>
#include <cstddef>

#define D 512
#define NHEAD 8
#define LMAX 512
#define NGIN 3

typedef unsigned short u16;
typedef unsigned long long u64;
typedef __attribute__((ext_vector_type(8))) short short8;
typedef __attribute__((ext_vector_type(8))) unsigned short ushort8;
typedef __attribute__((ext_vector_type(4))) unsigned short us4;
typedef __attribute__((ext_vector_type(4))) float f32x4;

static __device__ inline u16 f2bf(float f){
    union { float f; uint32_t u; } c; c.f = f;
    uint32_t r = (c.u + 0x7fffu + ((c.u >> 16) & 1u)) >> 16;
    return (u16)r;
}
static __device__ inline u16 tbf(float f){
    union { float f; uint32_t u; } c; c.f = f;
    return (u16)(c.u >> 16);
}
static __device__ inline float bf2f(u16 h){
    union { uint32_t u; float f; } c; c.u = ((uint32_t)h) << 16; return c.f;
}

#define GLOAD_LDS16(SRC, DST) \
    __builtin_amdgcn_global_load_lds( \
        (const __attribute__((address_space(1))) void*)(SRC), \
        (__attribute__((address_space(3))) void*)(DST), 16, 0, 0)

// ---------------- probe + memsets (one launch) ----------------
__global__ __launch_bounds__(256) void probe_mega(const int* __restrict__ ptr_raw,
        const unsigned char* __restrict__ mask_raw, int* __restrict__ flags,
        int* __restrict__ deg, int* __restrict__ cursor,
        float* __restrict__ sums, float* __restrict__ zbias, int N){
    int i = blockIdx.x*256 + threadIdx.x;
    if (i < N){ deg[i] = 0; cursor[i] = 0; }
    if (i < 1024){ sums[i] = 0.f; zbias[i] = 0.f; }
    if (blockIdx.x == 0 && threadIdx.x == 0){
        flags[0] = (ptr_raw[1] == 0) ? 1 : 0;
        int cntOdd = 0, cnt4 = 0;
        for (int k = 1; k < 2048; k += 2) cntOdd += (mask_raw[k] != 0);
        for (int k = 4; k < 2048; k += 8) cnt4   += (mask_raw[k] != 0);
        flags[1] = (cntOdd > 64) ? 1 : ((cnt4 > 16) ? 4 : 8);
    }
}

// ---------------- mega prologue: z-roles ----------------
__global__ __launch_bounds__(256) void mega_prologue(
        const float* __restrict__ v_w, const float* __restrict__ gin_w1,
        const float* __restrict__ gin_w2, const float* __restrict__ se_w,
        const float* __restrict__ out_w, const float* __restrict__ qk_w,
        u16* __restrict__ wtsh, u16* __restrict__ wtsl,
        const unsigned char* __restrict__ mask_raw, u64* __restrict__ mbits,
        const float* __restrict__ x, u16* __restrict__ Xh, u16* __restrict__ Xl,
        u16* __restrict__ sewh, u16* __restrict__ sewl,
        const int* __restrict__ ptr_raw, int* __restrict__ ptr32,
        const int* __restrict__ ei_raw, int* __restrict__ deg,
        const int* __restrict__ flags,
        int Nnodes, int E, int B, int Mn64){
    int z = blockIdx.z;
    int bid = blockIdx.y*32 + blockIdx.x;
    int tid = threadIdx.x;
    if (z <= 9){
        int Nout = (z == 9) ? 1024 : 512;
        if (z < 9 && blockIdx.x >= 16) return;
        const size_t SLOT = 262144;
        const float* W; int slot;
        switch (z){
            case 0: W = v_w; slot = 0; break;
            case 1: W = gin_w1;          slot = 1; break;
            case 2: W = gin_w2;          slot = 2; break;
            case 3: W = gin_w1 + 262144; slot = 3; break;
            case 4: W = gin_w2 + 262144; slot = 4; break;
            case 5: W = gin_w1 + 524288; slot = 5; break;
            case 6: W = gin_w2 + 524288; slot = 6; break;
            case 7: W = se_w;  slot = 7; break;
            case 8: W = out_w; slot = 10; break;
            default: W = qk_w; slot = 8; break;
        }
        u16* Wh = wtsh + SLOT*slot;
        u16* Wl = wtsl + SLOT*slot;
        __shared__ float T[32][33];
        int nb = blockIdx.x*32, kb = blockIdx.y*32;
        int ln = tid & 31, lk = tid >> 5;
        #pragma unroll
        for (int i = 0; i < 4; i++)
            T[lk + 8*i][ln] = W[(size_t)(kb + lk + 8*i)*Nout + nb + ln];
        __syncthreads();
        #pragma unroll
        for (int i = 0; i < 4; i++){
            float val = T[ln][lk + 8*i];
            u16 h = tbf(val);
            size_t idx = (size_t)(nb + lk + 8*i)*512 + kb + ln;
            Wh[idx] = h;
            Wl[idx] = tbf(val - bf2f(h));
        }
    } else if (z == 10){
        int idx = bid*256 + tid;
        if (idx >= Mn64) return;
        int w = flags[1];
        size_t ebase = (size_t)(idx >> 3) * 512 + (size_t)(idx & 7) * 64;
        u64 bits = 0;
        if (w == 1){
            const u64* p8 = (const u64*)(mask_raw + ebase);
            #pragma unroll
            for (int g = 0; g < 8; g++){
                u64 v = p8[g];
                #pragma unroll
                for (int by = 0; by < 8; by++)
                    if ((v >> (by*8)) & 0xffull) bits |= 1ull << (g*8 + by);
            }
        } else {
            for (int j = 0; j < 64; j++)
                if (mask_raw[(ebase + j) * (size_t)w]) bits |= 1ull << j;
        }
        mbits[idx] = bits;
    } else if (z == 11){
        int total4 = Nnodes*D/4;
        for (int i = bid*256 + tid; i < total4; i += 131072){
            float4 v = *(const float4*)(x + (size_t)i*4);
            float fv[4] = {v.x, v.y, v.z, v.w};
            us4 h4, l4;
            #pragma unroll
            for (int j = 0; j < 4; j++){
                u16 hh = tbf(fv[j]);
                h4[j] = hh;
                l4[j] = tbf(fv[j] - bf2f(hh));
            }
            *(us4*)(Xh + (size_t)i*4) = h4;
            *(us4*)(Xl + (size_t)i*4) = l4;
        }
    } else if (z == 12){
        int i = bid*256 + tid;
        if (i >= D*D/4) return;
        float4 v = *(const float4*)(se_w + (size_t)i*4);
        float fv[4] = {v.x, v.y, v.z, v.w};
        us4 h4, l4;
        #pragma unroll
        for (int j = 0; j < 4; j++){
            u16 hh = tbf(fv[j]);
            h4[j] = hh;
            l4[j] = tbf(fv[j] - bf2f(hh));
        }
        *(us4*)(sewh + (size_t)i*4) = h4;
        *(us4*)(sewl + (size_t)i*4) = l4;
    } else if (z == 13){
        if (bid == 0 && tid <= B)
            ptr32[tid] = flags[0] ? ptr_raw[2*tid] : ptr_raw[tid];
    } else {
        int e = bid*256 + tid;
        if (e < E){
            int d = flags[0] ? ei_raw[2*(E + e)] : ei_raw[E + e];
            if ((unsigned)d < (unsigned)Nnodes) atomicAdd(&deg[d], 1);
        }
    }
}

// ---------------- parallel scan: A (local) / B (bases); base-add folded into consumers ----------------
__global__ __launch_bounds__(1024) void scanA(const int* __restrict__ deg,
        int* __restrict__ offs, int* __restrict__ totals, int n){
    __shared__ int wsum[16];
    int ch = blockIdx.x;
    int tid = threadIdx.x, lane = tid & 63, wv = tid >> 6;
    int i = ch*1024 + tid;
    int val = (i < n) ? deg[i] : 0;
    int s = val;
    #pragma unroll
    for (int off = 1; off < 64; off <<= 1){
        int t = __shfl_up(s, off);
        if (lane >= off) s += t;
    }
    if (lane == 63) wsum[wv] = s;
    __syncthreads();
    if (wv == 0){
        int t = (lane < 16) ? wsum[lane] : 0;
        #pragma unroll
        for (int off = 1; off < 16; off <<= 1){
            int u = __shfl_up(t, off);
            if (lane >= off) t += u;
        }
        if (lane < 16) wsum[lane] = t;
    }
    __syncthreads();
    int wbase = wv ? wsum[wv-1] : 0;
    if (i < n) offs[i+1] = wbase + s;
    if (tid == 1023) totals[ch] = wsum[15];
    if (ch == 0 && tid == 0) offs[0] = 0;
}

__global__ void scanB(int* __restrict__ totals, int nch){
    int lane = threadIdx.x;
    int v = (lane < nch) ? totals[lane] : 0;
    int s = v;
    #pragma unroll
    for (int off = 1; off < 64; off <<= 1){
        int t = __shfl_up(s, off);
        if (lane >= off) s += t;
    }
    if (lane < nch) totals[lane] = s - v;   // exclusive chunk base
}

// offs_final[i] = offs[i] + (i>=1 ? totals[(i-1)>>10] : 0)
__global__ void fill_kernel(const int* __restrict__ ei_raw, const int* __restrict__ offs,
                            const int* __restrict__ totals,
                            int* __restrict__ cursor, int* __restrict__ in_src,
                            const int* __restrict__ flags, int E, int N){
    int e = blockIdx.x*256 + threadIdx.x;
    if (e < E){
        int d = flags[0] ? ei_raw[2*(E + e)] : ei_raw[E + e];
        if ((unsigned)d < (unsigned)N){
            int slot = atomicAdd(&cursor[d], 1);
            int start = offs[d] + (d ? totals[(d-1) >> 10] : 0);
            in_src[start + slot] = flags[0] ? ei_raw[2*e] : ei_raw[e];
        }
    }
}

// ---------------- gather ----------------
__global__ __launch_bounds__(256) void gather_kernel(const u16* __restrict__ hh,
        const u16* __restrict__ hl,
        const int* __restrict__ offs, const int* __restrict__ totals,
        const int* __restrict__ in_src,
        u16* __restrict__ oh, u16* __restrict__ ol, int N){
    int node = blockIdx.x*2 + (threadIdx.x >> 7);
    if (node >= N) return;
    int t = threadIdx.x & 127;
    size_t rb = (size_t)node*D + t*4;
    us4 vh = *(const us4*)(hh + rb);
    us4 vl = *(const us4*)(hl + rb);
    float a[4];
    #pragma unroll
    for (int j = 0; j < 4; j++) a[j] = bf2f(vh[j]) + bf2f(vl[j]);
    int s = offs[node] + (node ? totals[(node-1) >> 10] : 0);
    int e = offs[node+1] + totals[node >> 10];
    for (int i = s; i < e; i++){
        size_t sb = (size_t)in_src[i]*D + t*4;
        us4 nh = *(const us4*)(hh + sb);
        us4 nl = *(const us4*)(hl + sb);
        #pragma unroll
        for (int j = 0; j < 4; j++) a[j] += bf2f(nh[j]) + bf2f(nl[j]);
    }
    us4 h4, l4;
    #pragma unroll
    for (int j = 0; j < 4; j++){
        u16 hh2 = tbf(a[j]);
        h4[j] = hh2;
        l4[j] = tbf(a[j] - bf2f(hh2));
    }
    *(us4*)(oh + rb) = h4;
    *(us4*)(ol + rb) = l4;
}

// ---------------- fold mega ----------------
__global__ __launch_bounds__(256) void fold_mega(const float* __restrict__ M1,
        const float* __restrict__ sums, const float* __restrict__ gamma,
        const float* __restrict__ beta,
        const float* __restrict__ se_b, const float* __restrict__ qk_w,
        const float* __restrict__ qk_b,
        u16* __restrict__ Wh, u16* __restrict__ Wl, float* __restrict__ bbig, int n){
    float inv_n = 1.f / (float)n;
    if (blockIdx.z == 0){
        __shared__ float T[32][33];
        int nb = blockIdx.x*32, kb = blockIdx.y*32;
        int ln = threadIdx.x & 31, lk = threadIdx.x >> 5;
        #pragma unroll
        for (int i = 0; i < 4; i++){
            int k = kb + lk + 8*i;
            float mean = sums[k] * inv_n;
            float var = sums[512+k] * inv_n - mean*mean;
            float scale = rsqrtf(var + 1e-5f) * gamma[k];
            T[lk + 8*i][ln] = M1[(size_t)k*1024 + nb + ln] * scale;
        }
        __syncthreads();
        #pragma unroll
        for (int i = 0; i < 4; i++){
            float val = T[ln][lk + 8*i];
            u16 h = tbf(val);
            size_t idx = (size_t)(nb + lk + 8*i)*512 + kb + ln;
            Wh[idx] = h;
            Wl[idx] = tbf(val - bf2f(h));
        }
    } else {
        int wv = threadIdx.x >> 6, lane = threadIdx.x & 63;
        if (wv >= 2) return;
        int nidx = (blockIdx.y*32 + blockIdx.x)*2 + wv;
        float acc = 0.f;
        for (int k = lane; k < 512; k += 64){
            float mean = sums[k] * inv_n;
            float var = sums[512+k] * inv_n - mean*mean;
            float scale = rsqrtf(var + 1e-5f) * gamma[k];
            float shift = beta[k] - mean*scale;
            acc += shift*M1[(size_t)k*1024 + nidx] + se_b[k]*qk_w[(size_t)k*1024 + nidx];
        }
        #pragma unroll
        for (int off = 32; off > 0; off >>= 1) acc += __shfl_xor(acc, off);
        if (lane == 0) bbig[nidx] = acc + qk_b[nidx];
    }
}

// ---------------- shared GEMM body: 128x64 tile, 256 thr, 48KB LDS arena ----------------
template<int ACT, int EPI, int TERMS, int STATS>
__device__ __forceinline__ void gemm_body(char* ldsbase,
        const u16* __restrict__ Ahg, const u16* __restrict__ Alg,
        const u16* __restrict__ Wth, const u16* __restrict__ Wtl,
        const float* __restrict__ bias,
        void* __restrict__ C0, void* __restrict__ C1,
        float* __restrict__ stat_sums, int K, int Nout, int rowBase, int colBase){
    u16 (*Ah)[64] = (u16(*)[64])(ldsbase);
    u16 (*Al)[64] = (u16(*)[64])(ldsbase + 16384);
    u16 (*Bh)[64] = (u16(*)[64])(ldsbase + 32768);
    u16 (*Bl)[64] = (u16(*)[64])(ldsbase + 40960);
    int tid = threadIdx.x;
    int w = tid >> 6, l = tid & 63, lg = l >> 4, lm = l & 15;
    int wr = w >> 1, wc = w & 1;
    f32x4 acc[4][2] = {};
    const u16* Ahp = Ahg + (size_t)rowBase*K;
    const u16* Alp = (TERMS == 3) ? Alg + (size_t)rowBase*K : nullptr;
    const u16* Wph = Wth + (size_t)colBase*K;
    const u16* Wpl = Wtl + (size_t)colBase*K;
    int srowA[4], scolA[4], srowB[2], scolB[2];
    #pragma unroll
    for (int c = 0; c < 4; c++){
        int slot = c*256 + tid;
        srowA[c] = slot >> 3;
        scolA[c] = ((slot & 7) ^ (srowA[c] & 7)) * 8;
    }
    #pragma unroll
    for (int c = 0; c < 2; c++){
        int slot = c*256 + tid;
        srowB[c] = slot >> 3;
        scolB[c] = ((slot & 7) ^ (srowB[c] & 7)) * 8;
    }
    for (int k0 = 0; k0 < K; k0 += 64){
        #pragma unroll
        for (int c = 0; c < 4; c++){
            int slot = c*256 + tid;
            size_t so = (size_t)srowA[c]*K + k0 + scolA[c];
            GLOAD_LDS16(Ahp + so, &Ah[0][0] + slot*8);
            if (TERMS == 3) GLOAD_LDS16(Alp + so, &Al[0][0] + slot*8);
        }
        #pragma unroll
        for (int c = 0; c < 2; c++){
            int slot = c*256 + tid;
            size_t so = (size_t)srowB[c]*K + k0 + scolB[c];
            GLOAD_LDS16(Wph + so, &Bh[0][0] + slot*8);
            GLOAD_LDS16(Wpl + so, &Bl[0][0] + slot*8);
        }
        __syncthreads();
        #pragma unroll
        for (int ks = 0; ks < 2; ks++){
            int scg = ((ks*4 + lg) ^ (lm & 7)) * 8;
            short8 ah[4], al[4], bh[2], bl[2];
            #pragma unroll
            for (int mf = 0; mf < 4; mf++){
                ah[mf] = *(const short8*)&Ah[wr*64 + mf*16 + lm][scg];
                if (TERMS == 3) al[mf] = *(const short8*)&Al[wr*64 + mf*16 + lm][scg];
            }
            #pragma unroll
            for (int nf = 0; nf < 2; nf++){
                bh[nf] = *(const short8*)&Bh[wc*32 + nf*16 + lm][scg];
                bl[nf] = *(const short8*)&Bl[wc*32 + nf*16 + lm][scg];
            }
            __builtin_amdgcn_s_setprio(1);
            #pragma unroll
            for (int mf = 0; mf < 4; mf++)
                #pragma unroll
                for (int nf = 0; nf < 2; nf++){
                    acc[mf][nf] = __builtin_amdgcn_mfma_f32_16x16x32_bf16(ah[mf], bh[nf], acc[mf][nf], 0, 0, 0);
                    if (TERMS == 3)
                        acc[mf][nf] = __builtin_amdgcn_mfma_f32_16x16x32_bf16(al[mf], bh[nf], acc[mf][nf], 0, 0, 0);
                    acc[mf][nf] = __builtin_amdgcn_mfma_f32_16x16x32_bf16(ah[mf], bl[nf], acc[mf][nf], 0, 0, 0);
                }
            __builtin_amdgcn_s_setprio(0);
        }
        __syncthreads();
    }
    #pragma unroll
    for (int nf = 0; nf < 2; nf++){
        int col = colBase + wc*32 + nf*16 + lm;
        float bv = bias[col];
        float ssum = 0.f, ssq = 0.f;
        #pragma unroll
        for (int mf = 0; mf < 4; mf++){
            int row = rowBase + wr*64 + mf*16 + lg*4;
            #pragma unroll
            for (int j = 0; j < 4; j++){
                float o = acc[mf][nf][j] + bv;
                if (ACT) o = fmaxf(o, 0.f);
                if (STATS){ ssum += o; ssq += o*o; }
                size_t idx = (size_t)(row + j)*Nout + col;
                if (EPI == 0){
                    ((float*)C0)[idx] = o;
                } else if (EPI == 1){
                    u16 hh = tbf(o);
                    ((u16*)C0)[idx] = hh;
                    ((u16*)C1)[idx] = tbf(o - bf2f(hh));
                } else {
                    ((u16*)C0)[idx] = f2bf(o);
                }
            }
        }
        if (STATS){
            ssum += __shfl_xor(ssum, 16); ssum += __shfl_xor(ssum, 32);
            ssq  += __shfl_xor(ssq, 16);  ssq  += __shfl_xor(ssq, 32);
            if (lg == 0){
                atomicAdd(&stat_sums[col], ssum);
                atomicAdd(&stat_sums[512 + col], ssq);
            }
        }
    }
}

static __device__ inline void xcd_tile(int gx, int gy, int& rowBase, int& colBase){
    int nwg = gx * gy;
    int orig = blockIdx.x + gx*blockIdx.y;
    int q8 = nwg >> 3, r8 = nwg & 7;
    int xcd = orig & 7, pos = orig >> 3;
    int wg = (xcd < r8 ? xcd*(q8+1) : r8*(q8+1) + (xcd - r8)*q8) + pos;
    rowBase = (wg / gx) * 128;
    colBase = (wg % gx) * 64;
}

// standalone GEMM kernel
template<int ACT, int EPI, int TERMS, int STATS>
__global__ __launch_bounds__(256) void gemm_ps(const u16* __restrict__ Ahg,
        const u16* __restrict__ Alg,
        const u16* __restrict__ Wth, const u16* __restrict__ Wtl,
        const float* __restrict__ bias,
        void* __restrict__ C0, void* __restrict__ C1,
        float* __restrict__ stat_sums, int K, int Nout){
    __shared__ __align__(16) char lds[49152];
    int rowBase, colBase;
    xcd_tile(gridDim.x, gridDim.y, rowBase, colBase);
    gemm_body<ACT,EPI,TERMS,STATS>(lds, Ahg, Alg, Wth, Wtl, bias, C0, C1, stat_sums, K, Nout, rowBase, colBase);
}

// triple-merged launch: z=0 GIN-1a, z=1 v GEMM, z=2 M1
__global__ __launch_bounds__(256) void triple_gemm(
        const u16* __restrict__ Gh, const u16* __restrict__ Gl,
        const u16* __restrict__ w1h, const u16* __restrict__ w1l,
        const float* __restrict__ b1, u16* __restrict__ Th, u16* __restrict__ Tl,
        const u16* __restrict__ Xh,
        const u16* __restrict__ wvh, const u16* __restrict__ wvl,
        const float* __restrict__ vb, u16* __restrict__ vbf,
        const u16* __restrict__ sewh, const u16* __restrict__ sewl,
        const u16* __restrict__ wqkh, const u16* __restrict__ wqkl,
        const float* __restrict__ zbias, float* __restrict__ M1){
    __shared__ __align__(16) char lds[49152];
    int z = blockIdx.z;
    if (z <= 1){
        int rowBase, colBase;
        xcd_tile(gridDim.x, gridDim.y, rowBase, colBase);
        if (z == 0)
            gemm_body<1,1,3,0>(lds, Gh, Gl, w1h, w1l, b1, Th, Tl, nullptr, 512, 512, rowBase, colBase);
        else
            gemm_body<0,2,2,0>(lds, Xh, nullptr, wvh, wvl, vb, vbf, nullptr, nullptr, 512, 512, rowBase, colBase);
    } else {
        int orig = blockIdx.x + gridDim.x*blockIdx.y;
        if (orig >= 64) return;
        int rowBase = (orig >> 4) * 128, colBase = (orig & 15) * 64;
        gemm_body<0,0,3,0>(lds, sewh, sewl, wqkh, wqkl, zbias, M1, nullptr, nullptr, 512, 1024, rowBase, colBase);
    }
}

// ---------------- MFMA ragged masked flash attention, 128-row q-blocks ----------------
// XCD relabel v2: xcd = head (balanced — every head has identical total work);
// within an XCD, q-block siblings of each (b,h) are consecutive -> K/V L2 reuse.
#define ATS 72
__global__ __launch_bounds__(512) void attn_mfma_kernel(const u16* __restrict__ qkH,
        const u16* __restrict__ qkL, const u16* __restrict__ vbf,
        const u64* __restrict__ maskbits,
        const int* __restrict__ ptr, u16* __restrict__ oh, int N){
    __shared__ u16 Kh[64][ATS];
    __shared__ u16 Kl[64][ATS];
    __shared__ u16 Vt[64][ATS];
    __shared__ u16 Pl[8][16][ATS];
    int orig = blockIdx.x + 4*blockIdx.y + 32*blockIdx.z;
    int xcd = orig & 7, pos = orig >> 3;
    int h  = xcd;                 // one head per XCD: perfectly balanced
    int b  = pos >> 2;            // 32 graphs per XCD
    int q0 = (pos & 3) * 128;     // q-siblings consecutive -> co-XCD K/V reuse
    int base = ptr[b], size = ptr[b+1] - base;
    if (q0 >= size) return;
    int tid = threadIdx.x, w = tid >> 6, l = tid & 63;
    int lg = l >> 4, lm = l & 15;
    short8 qh[2], ql[2];
    {
        int qrow = q0 + w*16 + lm;
        int qr = (qrow < size) ? qrow : 0;
        const u16* qph = qkH + (size_t)(base + qr)*1024 + 512 + h*64;
        const u16* qpl = qkL + (size_t)(base + qr)*1024 + 512 + h*64;
        #pragma unroll
        for (int ks = 0; ks < 2; ks++){
            short8 th = *(const short8*)(qph + ks*32 + lg*8);
            short8 tl = *(const short8*)(qpl + ks*32 + lg*8);
            if (qrow >= size){ th = short8{0,0,0,0,0,0,0,0}; tl = short8{0,0,0,0,0,0,0,0}; }
            qh[ks] = th; ql[ks] = tl;
        }
    }
    f32x4 acco[4] = {};
    float mrow[4], lrow[4];
    #pragma unroll
    for (int j = 0; j < 4; j++){ mrow[j] = -INFINITY; lrow[j] = 0.f; }
    int nt = (size + 63) >> 6;
    for (int t = 0; t < nt; t++){
        int j0 = t*64;
        __syncthreads();
        {
            int jj = tid & 63, db = (tid >> 6)*8;
            int key = j0 + jj;
            bool ok = key < size;
            size_t node = (size_t)(base + (ok ? key : 0));
            const u16* khp = qkH + node*1024 + h*64 + db;
            const u16* klp = qkL + node*1024 + h*64 + db;
            const u16* vp  = vbf + node*512  + h*64 + db;
            ushort8 z = {0,0,0,0,0,0,0,0};
            ushort8 kh0 = ok ? *(const ushort8*)(khp) : z;
            ushort8 kl0 = ok ? *(const ushort8*)(klp) : z;
            ushort8 v0  = ok ? *(const ushort8*)(vp)  : z;
            *(ushort8*)&Kh[jj][db] = kh0;
            *(ushort8*)&Kl[jj][db] = kl0;
            #pragma unroll
            for (int i = 0; i < 8; i++) Vt[db + i][jj] = v0[i];
        }
        __syncthreads();
        f32x4 sc[4] = {};
        __builtin_amdgcn_s_setprio(1);
        #pragma unroll
        for (int nf = 0; nf < 4; nf++)
            #pragma unroll
            for (int ks = 0; ks < 2; ks++){
                short8 kh = *(const short8*)&Kh[nf*16 + lm][ks*32 + lg*8];
                short8 kl = *(const short8*)&Kl[nf*16 + lm][ks*32 + lg*8];
                sc[nf] = __builtin_amdgcn_mfma_f32_16x16x32_bf16(qh[ks], kh, sc[nf], 0, 0, 0);
                sc[nf] = __builtin_amdgcn_mfma_f32_16x16x32_bf16(ql[ks], kh, sc[nf], 0, 0, 0);
                sc[nf] = __builtin_amdgcn_mfma_f32_16x16x32_bf16(qh[ks], kl, sc[nf], 0, 0, 0);
            }
        __builtin_amdgcn_s_setprio(0);
        u64 mb[4];
        #pragma unroll
        for (int j = 0; j < 4; j++)
            mb[j] = maskbits[((size_t)b*LMAX + (q0 + w*16 + lg*4 + j))*8 + t];
        float mx[4], alpha[4];
        #pragma unroll
        for (int j = 0; j < 4; j++){
            float s0 = -INFINITY;
            #pragma unroll
            for (int nf = 0; nf < 4; nf++){
                int key = j0 + nf*16 + lm;
                float s = sc[nf][j] * 0.125f;
                bool msk = (key >= size) || ((mb[j] >> (nf*16 + lm)) & 1);
                s = msk ? -INFINITY : s;
                sc[nf][j] = s;
                s0 = fmaxf(s0, s);
            }
            #pragma unroll
            for (int off = 1; off < 16; off <<= 1) s0 = fmaxf(s0, __shfl_xor(s0, off));
            mx[j] = s0;
        }
        #pragma unroll
        for (int j = 0; j < 4; j++){
            if (mx[j] == -INFINITY){ alpha[j] = 1.f; }
            else {
                float mn = fmaxf(mrow[j], mx[j]);
                alpha[j] = __expf(mrow[j] - mn);
                mrow[j] = mn;
            }
        }
        float ps[4] = {0.f, 0.f, 0.f, 0.f};
        #pragma unroll
        for (int nf = 0; nf < 4; nf++)
            #pragma unroll
            for (int j = 0; j < 4; j++){
                float p = (mx[j] == -INFINITY) ? 0.f : __expf(sc[nf][j] - mrow[j]);
                ps[j] += p;
                Pl[w][lg*4 + j][nf*16 + lm] = tbf(p);
            }
        #pragma unroll
        for (int j = 0; j < 4; j++){
            float s = ps[j];
            #pragma unroll
            for (int off = 1; off < 16; off <<= 1) s += __shfl_xor(s, off);
            lrow[j] = lrow[j]*alpha[j] + s;
        }
        #pragma unroll
        for (int df = 0; df < 4; df++)
            #pragma unroll
            for (int j = 0; j < 4; j++) acco[df][j] *= alpha[j];
        __builtin_amdgcn_s_setprio(1);
        #pragma unroll
        for (int ks = 0; ks < 2; ks++){
            short8 pf = *(const short8*)&Pl[w][lm][ks*32 + lg*8];
            #pragma unroll
            for (int df = 0; df < 4; df++){
                short8 vf = *(const short8*)&Vt[df*16 + lm][ks*32 + lg*8];
                acco[df] = __builtin_amdgcn_mfma_f32_16x16x32_bf16(pf, vf, acco[df], 0, 0, 0);
            }
        }
        __builtin_amdgcn_s_setprio(0);
    }
    #pragma unroll
    for (int j = 0; j < 4; j++){
        int r = q0 + w*16 + lg*4 + j;
        if (r < size){
            float inv = 1.f / lrow[j];
            #pragma unroll
            for (int df = 0; df < 4; df++){
                float o = acco[df][j] * inv;
                oh[(size_t)(base + r)*D + h*64 + df*16 + lm] = f2bf(o);
            }
        }
    }
}

extern "C" void kernel_launch(void* const* d_in, const int* in_sizes, int n_in,
                              void* d_out, int out_size, void* d_ws, size_t ws_size,
                              hipStream_t stream){
    const float* x        = (const float*)d_in[0];
    const int*   ei_raw   = (const int*)d_in[1];
    const unsigned char* mask_raw = (const unsigned char*)d_in[2];
    const int*   ptr_raw  = (const int*)d_in[3];
    const float* gin_w1   = (const float*)d_in[4];
    const float* gin_b1   = (const float*)d_in[5];
    const float* gin_w2   = (const float*)d_in[6];
    const float* gin_b2   = (const float*)d_in[7];
    const float* bn_gamma = (const float*)d_in[8];
    const float* bn_beta  = (const float*)d_in[9];
    const float* se_w     = (const float*)d_in[10];
    const float* se_b     = (const float*)d_in[11];
    const float* qk_w     = (const float*)d_in[12];
    const float* qk_b     = (const float*)d_in[13];
    const float* v_w      = (const float*)d_in[14];
    const float* v_b      = (const float*)d_in[15];
    const float* out_w    = (const float*)d_in[16];
    const float* out_b    = (const float*)d_in[17];

    const int N  = in_sizes[0] / D;       // 12160
    const int E  = in_sizes[1] / 2;       // 97280
    const int B  = in_sizes[3] - 1;       // 32
    const int Mn = in_sizes[2];           // B*512*512

    char* ws = (char*)d_ws;
    char* p = ws;
    auto alloc = [&](size_t bytes) -> char* {
        char* q = p; p += (bytes + 255) & ~(size_t)255; return q;
    };
    size_t PLANE = (size_t)N * D * sizeof(u16);
    u16* pairX = (u16*)alloc(2*PLANE);
    u16* pairG = (u16*)alloc(2*PLANE);
    u16* pairT = (u16*)alloc(2*PLANE);
    u16* pairH = (u16*)alloc(2*PLANE);
    u16* v_bf  = (u16*)alloc(PLANE);
    u16* Xh = pairX, *Xl = pairX + (size_t)N*D;
    u16* Gh = pairG, *Gl = pairG + (size_t)N*D;
    u16* Th = pairT, *Tl = pairT + (size_t)N*D;
    u16* Hh = pairH, *Hl = pairH + (size_t)N*D;
    float* sums   = (float*)alloc(1024*sizeof(float));
    int*   flags  = (int*)alloc(16*sizeof(int));
    int*   deg    = (int*)alloc((size_t)N*sizeof(int));
    int*   offs   = (int*)alloc((size_t)(N+1)*sizeof(int));
    int*   cursor = (int*)alloc((size_t)N*sizeof(int));
    int*   in_src = (int*)alloc((size_t)E*sizeof(int));
    int*   ptr32  = (int*)alloc(64*sizeof(int));
    int*   totals = (int*)alloc(64*sizeof(int));
    u64*   mbits  = (u64*)alloc((size_t)(Mn/64)*sizeof(u64));
    u16*   wtsh   = (u16*)alloc((size_t)2883584*sizeof(u16));
    u16*   wtsl   = (u16*)alloc((size_t)2883584*sizeof(u16));
    u16*   sewh   = (u16*)alloc((size_t)D*D*sizeof(u16));
    u16*   sewl   = (u16*)alloc((size_t)D*D*sizeof(u16));
    float* M1     = (float*)alloc((size_t)D*1024*sizeof(float));
    u16*   wbig_h = (u16*)alloc((size_t)1024*D*sizeof(u16));
    u16*   wbig_l = (u16*)alloc((size_t)1024*D*sizeof(u16));
    float* bbig   = (float*)alloc(1024*sizeof(float));
    float* zbias  = (float*)alloc(1024*sizeof(float));
    const size_t SLOT = 262144;
    u16 *wh_v = wtsh, *wl_v = wtsl;
    u16 *wh_g[6], *wl_g[6];
    for (int i = 0; i < 6; i++){ wh_g[i] = wtsh + SLOT*(1+i); wl_g[i] = wtsl + SLOT*(1+i); }
    u16 *wh_qk  = wtsh + SLOT*8,  *wl_qk  = wtsl + SLOT*8;
    u16 *wh_out = wtsh + SLOT*10, *wl_out = wtsl + SLOT*10;

    // --- probe + memsets, mega prologue ---
    probe_mega<<<(N + 255)/256, 256, 0, stream>>>(ptr_raw, mask_raw, flags,
        deg, cursor, sums, zbias, N);
    mega_prologue<<<dim3(32,16,15), 256, 0, stream>>>(
        v_w, gin_w1, gin_w2, se_w, out_w, qk_w, wtsh, wtsl,
        mask_raw, mbits, x, Xh, Xl, sewh, sewl,
        ptr_raw, ptr32, ei_raw, deg, flags, N, E, B, Mn/64);
    int nch = (N + 1023)/1024;
    scanA<<<nch, 1024, 0, stream>>>(deg, offs, totals, N);
    scanB<<<1, 64, 0, stream>>>(totals, nch);
    fill_kernel<<<(E+255)/256, 256, 0, stream>>>(ei_raw, offs, totals, cursor, in_src, flags, E, N);

    dim3 g512(8, N/128), g1024(16, N/128);

    // GIN layer 0: gather, then triple launch {GIN-1a, v GEMM, M1}
    gather_kernel<<<(N+1)/2, 256, 0, stream>>>(Xh, Xl, offs, totals, in_src, Gh, Gl, N);
    triple_gemm<<<dim3(8, N/128, 3), 256, 0, stream>>>(
        Gh, Gl, wh_g[0], wl_g[0], gin_b1, Th, Tl,
        Xh, wh_v, wl_v, v_b, v_bf,
        sewh, sewl, wh_qk, wl_qk, zbias, M1);
    gemm_ps<1,1,3,0><<<g512, 256, 0, stream>>>(Th, Tl, wh_g[1], wl_g[1], gin_b2, Hh, Hl, nullptr, D, D);

    // GIN layers 1..2
    for (int i = 1; i < NGIN; i++){
        gather_kernel<<<(N+1)/2, 256, 0, stream>>>(Hh, Hl, offs, totals, in_src, Gh, Gl, N);
        gemm_ps<1,1,3,0><<<g512, 256, 0, stream>>>(Gh, Gl, wh_g[2*i], wl_g[2*i], gin_b1 + (size_t)i*D, Th, Tl, nullptr, D, D);
        if (i == NGIN - 1)
            gemm_ps<1,1,3,1><<<g512, 256, 0, stream>>>(Th, Tl, wh_g[2*i+1], wl_g[2*i+1], gin_b2 + (size_t)i*D, Hh, Hl, sums, D, D);
        else
            gemm_ps<1,1,3,0><<<g512, 256, 0, stream>>>(Th, Tl, wh_g[2*i+1], wl_g[2*i+1], gin_b2 + (size_t)i*D, Hh, Hl, nullptr, D, D);
    }

    // fold BN + se into qk weight
    fold_mega<<<dim3(32,16,2), 256, 0, stream>>>(M1, sums, bn_gamma, bn_beta,
        se_b, qk_w, qk_b, wbig_h, wbig_l, bbig, N);

    // qk = gin_out @ Wbig + bbig -> hi plane = pairX (N x 1024), lo plane = pairG
    gemm_ps<0,1,3,0><<<g1024, 256, 0, stream>>>(Hh, Hl, wbig_h, wbig_l, bbig, pairX, pairG, nullptr, D, 2*D);

    // attention (balanced XCD swizzle): split qk + bf16 v -> plain bf16 output in Th
    attn_mfma_kernel<<<dim3(LMAX/128, NHEAD, B), 512, 0, stream>>>(pairX, pairG, v_bf, mbits, ptr32, Th, N);

    // out = attn_out @ out_w + out_b -> f32 d_out (2-term)
    gemm_ps<0,0,2,0><<<g512, 256, 0, stream>>>(Th, nullptr, wh_out, wl_out, out_b, (float*)d_out, nullptr, nullptr, D, D);
}

// Round 21
// 477.809 us; speedup vs baseline: 1.0439x; 1.0140x over previous
//
#include <hip/hip_runtime.h>
#include <hip/hip_bf16.h>
#include <cstdint>
#include <cstddef>

#define D 512
#define NHEAD 8
#define LMAX 512
#define NGIN 3

typedef unsigned short u16;
typedef unsigned long long u64;
typedef __attribute__((ext_vector_type(8))) short short8;
typedef __attribute__((ext_vector_type(8))) unsigned short ushort8;
typedef __attribute__((ext_vector_type(4))) unsigned short us4;
typedef __attribute__((ext_vector_type(4))) float f32x4;

static __device__ inline u16 f2bf(float f){
    union { float f; uint32_t u; } c; c.f = f;
    uint32_t r = (c.u + 0x7fffu + ((c.u >> 16) & 1u)) >> 16;
    return (u16)r;
}
static __device__ inline u16 tbf(float f){
    union { float f; uint32_t u; } c; c.f = f;
    return (u16)(c.u >> 16);
}
static __device__ inline float bf2f(u16 h){
    union { uint32_t u; float f; } c; c.u = ((uint32_t)h) << 16; return c.f;
}

#define GLOAD_LDS16(SRC, DST) \
    __builtin_amdgcn_global_load_lds( \
        (const __attribute__((address_space(1))) void*)(SRC), \
        (__attribute__((address_space(3))) void*)(DST), 16, 0, 0)

// ---------------- probe + memsets (one launch) ----------------
__global__ __launch_bounds__(256) void probe_mega(const int* __restrict__ ptr_raw,
        const unsigned char* __restrict__ mask_raw, int* __restrict__ flags,
        int* __restrict__ deg, int* __restrict__ cursor,
        float* __restrict__ sums, float* __restrict__ zbias, int N){
    int i = blockIdx.x*256 + threadIdx.x;
    if (i < N){ deg[i] = 0; cursor[i] = 0; }
    if (i < 1024){ sums[i] = 0.f; zbias[i] = 0.f; }
    if (blockIdx.x == 0 && threadIdx.x == 0){
        flags[0] = (ptr_raw[1] == 0) ? 1 : 0;
        int cntOdd = 0, cnt4 = 0;
        for (int k = 1; k < 2048; k += 2) cntOdd += (mask_raw[k] != 0);
        for (int k = 4; k < 2048; k += 8) cnt4   += (mask_raw[k] != 0);
        flags[1] = (cntOdd > 64) ? 1 : ((cnt4 > 16) ? 4 : 8);
    }
}

// ---------------- mega prologue: z-roles ----------------
__global__ __launch_bounds__(256) void mega_prologue(
        const float* __restrict__ v_w, const float* __restrict__ gin_w1,
        const float* __restrict__ gin_w2, const float* __restrict__ se_w,
        const float* __restrict__ out_w, const float* __restrict__ qk_w,
        u16* __restrict__ wtsh, u16* __restrict__ wtsl,
        const unsigned char* __restrict__ mask_raw, u64* __restrict__ mbits,
        const float* __restrict__ x, u16* __restrict__ Xh, u16* __restrict__ Xl,
        u16* __restrict__ sewh, u16* __restrict__ sewl,
        const int* __restrict__ ptr_raw, int* __restrict__ ptr32,
        const int* __restrict__ ei_raw, int* __restrict__ deg,
        const int* __restrict__ flags,
        int Nnodes, int E, int B, int Mn64){
    int z = blockIdx.z;
    int bid = blockIdx.y*32 + blockIdx.x;
    int tid = threadIdx.x;
    if (z <= 9){
        int Nout = (z == 9) ? 1024 : 512;
        if (z < 9 && blockIdx.x >= 16) return;
        const size_t SLOT = 262144;
        const float* W; int slot;
        switch (z){
            case 0: W = v_w; slot = 0; break;
            case 1: W = gin_w1;          slot = 1; break;
            case 2: W = gin_w2;          slot = 2; break;
            case 3: W = gin_w1 + 262144; slot = 3; break;
            case 4: W = gin_w2 + 262144; slot = 4; break;
            case 5: W = gin_w1 + 524288; slot = 5; break;
            case 6: W = gin_w2 + 524288; slot = 6; break;
            case 7: W = se_w;  slot = 7; break;
            case 8: W = out_w; slot = 10; break;
            default: W = qk_w; slot = 8; break;
        }
        u16* Wh = wtsh + SLOT*slot;
        u16* Wl = wtsl + SLOT*slot;
        __shared__ float T[32][33];
        int nb = blockIdx.x*32, kb = blockIdx.y*32;
        int ln = tid & 31, lk = tid >> 5;
        #pragma unroll
        for (int i = 0; i < 4; i++)
            T[lk + 8*i][ln] = W[(size_t)(kb + lk + 8*i)*Nout + nb + ln];
        __syncthreads();
        #pragma unroll
        for (int i = 0; i < 4; i++){
            float val = T[ln][lk + 8*i];
            u16 h = tbf(val);
            size_t idx = (size_t)(nb + lk + 8*i)*512 + kb + ln;
            Wh[idx] = h;
            Wl[idx] = tbf(val - bf2f(h));
        }
    } else if (z == 10){
        int idx = bid*256 + tid;
        if (idx >= Mn64) return;
        int w = flags[1];
        size_t ebase = (size_t)(idx >> 3) * 512 + (size_t)(idx & 7) * 64;
        u64 bits = 0;
        if (w == 1){
            const u64* p8 = (const u64*)(mask_raw + ebase);
            #pragma unroll
            for (int g = 0; g < 8; g++){
                u64 v = p8[g];
                #pragma unroll
                for (int by = 0; by < 8; by++)
                    if ((v >> (by*8)) & 0xffull) bits |= 1ull << (g*8 + by);
            }
        } else {
            for (int j = 0; j < 64; j++)
                if (mask_raw[(ebase + j) * (size_t)w]) bits |= 1ull << j;
        }
        mbits[idx] = bits;
    } else if (z == 11){
        int total4 = Nnodes*D/4;
        for (int i = bid*256 + tid; i < total4; i += 131072){
            float4 v = *(const float4*)(x + (size_t)i*4);
            float fv[4] = {v.x, v.y, v.z, v.w};
            us4 h4, l4;
            #pragma unroll
            for (int j = 0; j < 4; j++){
                u16 hh = tbf(fv[j]);
                h4[j] = hh;
                l4[j] = tbf(fv[j] - bf2f(hh));
            }
            *(us4*)(Xh + (size_t)i*4) = h4;
            *(us4*)(Xl + (size_t)i*4) = l4;
        }
    } else if (z == 12){
        int i = bid*256 + tid;
        if (i >= D*D/4) return;
        float4 v = *(const float4*)(se_w + (size_t)i*4);
        float fv[4] = {v.x, v.y, v.z, v.w};
        us4 h4, l4;
        #pragma unroll
        for (int j = 0; j < 4; j++){
            u16 hh = tbf(fv[j]);
            h4[j] = hh;
            l4[j] = tbf(fv[j] - bf2f(hh));
        }
        *(us4*)(sewh + (size_t)i*4) = h4;
        *(us4*)(sewl + (size_t)i*4) = l4;
    } else if (z == 13){
        if (bid == 0 && tid <= B)
            ptr32[tid] = flags[0] ? ptr_raw[2*tid] : ptr_raw[tid];
    } else {
        int e = bid*256 + tid;
        if (e < E){
            int d = flags[0] ? ei_raw[2*(E + e)] : ei_raw[E + e];
            if ((unsigned)d < (unsigned)Nnodes) atomicAdd(&deg[d], 1);
        }
    }
}

// ---------------- parallel scan: A (local) / B (bases); base-add folded into consumers ----------------
__global__ __launch_bounds__(1024) void scanA(const int* __restrict__ deg,
        int* __restrict__ offs, int* __restrict__ totals, int n){
    __shared__ int wsum[16];
    int ch = blockIdx.x;
    int tid = threadIdx.x, lane = tid & 63, wv = tid >> 6;
    int i = ch*1024 + tid;
    int val = (i < n) ? deg[i] : 0;
    int s = val;
    #pragma unroll
    for (int off = 1; off < 64; off <<= 1){
        int t = __shfl_up(s, off);
        if (lane >= off) s += t;
    }
    if (lane == 63) wsum[wv] = s;
    __syncthreads();
    if (wv == 0){
        int t = (lane < 16) ? wsum[lane] : 0;
        #pragma unroll
        for (int off = 1; off < 16; off <<= 1){
            int u = __shfl_up(t, off);
            if (lane >= off) t += u;
        }
        if (lane < 16) wsum[lane] = t;
    }
    __syncthreads();
    int wbase = wv ? wsum[wv-1] : 0;
    if (i < n) offs[i+1] = wbase + s;
    if (tid == 1023) totals[ch] = wsum[15];
    if (ch == 0 && tid == 0) offs[0] = 0;
}

__global__ void scanB(int* __restrict__ totals, int nch){
    int lane = threadIdx.x;
    int v = (lane < nch) ? totals[lane] : 0;
    int s = v;
    #pragma unroll
    for (int off = 1; off < 64; off <<= 1){
        int t = __shfl_up(s, off);
        if (lane >= off) s += t;
    }
    if (lane < nch) totals[lane] = s - v;   // exclusive chunk base
}

// offs_final[i] = offs[i] + (i>=1 ? totals[(i-1)>>10] : 0)
__global__ void fill_kernel(const int* __restrict__ ei_raw, const int* __restrict__ offs,
                            const int* __restrict__ totals,
                            int* __restrict__ cursor, int* __restrict__ in_src,
                            const int* __restrict__ flags, int E, int N){
    int e = blockIdx.x*256 + threadIdx.x;
    if (e < E){
        int d = flags[0] ? ei_raw[2*(E + e)] : ei_raw[E + e];
        if ((unsigned)d < (unsigned)N){
            int slot = atomicAdd(&cursor[d], 1);
            int start = offs[d] + (d ? totals[(d-1) >> 10] : 0);
            in_src[start + slot] = flags[0] ? ei_raw[2*e] : ei_raw[e];
        }
    }
}

// ---------------- gather ----------------
__global__ __launch_bounds__(256) void gather_kernel(const u16* __restrict__ hh,
        const u16* __restrict__ hl,
        const int* __restrict__ offs, const int* __restrict__ totals,
        const int* __restrict__ in_src,
        u16* __restrict__ oh, u16* __restrict__ ol, int N){
    int node = blockIdx.x*2 + (threadIdx.x >> 7);
    if (node >= N) return;
    int t = threadIdx.x & 127;
    size_t rb = (size_t)node*D + t*4;
    us4 vh = *(const us4*)(hh + rb);
    us4 vl = *(const us4*)(hl + rb);
    float a[4];
    #pragma unroll
    for (int j = 0; j < 4; j++) a[j] = bf2f(vh[j]) + bf2f(vl[j]);
    int s = offs[node] + (node ? totals[(node-1) >> 10] : 0);
    int e = offs[node+1] + totals[node >> 10];
    for (int i = s; i < e; i++){
        size_t sb = (size_t)in_src[i]*D + t*4;
        us4 nh = *(const us4*)(hh + sb);
        us4 nl = *(const us4*)(hl + sb);
        #pragma unroll
        for (int j = 0; j < 4; j++) a[j] += bf2f(nh[j]) + bf2f(nl[j]);
    }
    us4 h4, l4;
    #pragma unroll
    for (int j = 0; j < 4; j++){
        u16 hh2 = tbf(a[j]);
        h4[j] = hh2;
        l4[j] = tbf(a[j] - bf2f(hh2));
    }
    *(us4*)(oh + rb) = h4;
    *(us4*)(ol + rb) = l4;
}

// ---------------- fold mega ----------------
__global__ __launch_bounds__(256) void fold_mega(const float* __restrict__ M1,
        const float* __restrict__ sums, const float* __restrict__ gamma,
        const float* __restrict__ beta,
        const float* __restrict__ se_b, const float* __restrict__ qk_w,
        const float* __restrict__ qk_b,
        u16* __restrict__ Wh, u16* __restrict__ Wl, float* __restrict__ bbig, int n){
    float inv_n = 1.f / (float)n;
    if (blockIdx.z == 0){
        __shared__ float T[32][33];
        int nb = blockIdx.x*32, kb = blockIdx.y*32;
        int ln = threadIdx.x & 31, lk = threadIdx.x >> 5;
        #pragma unroll
        for (int i = 0; i < 4; i++){
            int k = kb + lk + 8*i;
            float mean = sums[k] * inv_n;
            float var = sums[512+k] * inv_n - mean*mean;
            float scale = rsqrtf(var + 1e-5f) * gamma[k];
            T[lk + 8*i][ln] = M1[(size_t)k*1024 + nb + ln] * scale;
        }
        __syncthreads();
        #pragma unroll
        for (int i = 0; i < 4; i++){
            float val = T[ln][lk + 8*i];
            u16 h = tbf(val);
            size_t idx = (size_t)(nb + lk + 8*i)*512 + kb + ln;
            Wh[idx] = h;
            Wl[idx] = tbf(val - bf2f(h));
        }
    } else {
        int wv = threadIdx.x >> 6, lane = threadIdx.x & 63;
        if (wv >= 2) return;
        int nidx = (blockIdx.y*32 + blockIdx.x)*2 + wv;
        float acc = 0.f;
        for (int k = lane; k < 512; k += 64){
            float mean = sums[k] * inv_n;
            float var = sums[512+k] * inv_n - mean*mean;
            float scale = rsqrtf(var + 1e-5f) * gamma[k];
            float shift = beta[k] - mean*scale;
            acc += shift*M1[(size_t)k*1024 + nidx] + se_b[k]*qk_w[(size_t)k*1024 + nidx];
        }
        #pragma unroll
        for (int off = 32; off > 0; off >>= 1) acc += __shfl_xor(acc, off);
        if (lane == 0) bbig[nidx] = acc + qk_b[nidx];
    }
}

// ---------------- shared GEMM body: 128x64 tile, 256 thr, 48KB LDS arena ----------------
template<int ACT, int EPI, int TERMS, int STATS>
__device__ __forceinline__ void gemm_body(char* ldsbase,
        const u16* __restrict__ Ahg, const u16* __restrict__ Alg,
        const u16* __restrict__ Wth, const u16* __restrict__ Wtl,
        const float* __restrict__ bias,
        void* __restrict__ C0, void* __restrict__ C1,
        float* __restrict__ stat_sums, int K, int Nout, int rowBase, int colBase){
    u16 (*Ah)[64] = (u16(*)[64])(ldsbase);
    u16 (*Al)[64] = (u16(*)[64])(ldsbase + 16384);
    u16 (*Bh)[64] = (u16(*)[64])(ldsbase + 32768);
    u16 (*Bl)[64] = (u16(*)[64])(ldsbase + 40960);
    int tid = threadIdx.x;
    int w = tid >> 6, l = tid & 63, lg = l >> 4, lm = l & 15;
    int wr = w >> 1, wc = w & 1;
    f32x4 acc[4][2] = {};
    const u16* Ahp = Ahg + (size_t)rowBase*K;
    const u16* Alp = (TERMS == 3) ? Alg + (size_t)rowBase*K : nullptr;
    const u16* Wph = Wth + (size_t)colBase*K;
    const u16* Wpl = Wtl + (size_t)colBase*K;
    int srowA[4], scolA[4], srowB[2], scolB[2];
    #pragma unroll
    for (int c = 0; c < 4; c++){
        int slot = c*256 + tid;
        srowA[c] = slot >> 3;
        scolA[c] = ((slot & 7) ^ (srowA[c] & 7)) * 8;
    }
    #pragma unroll
    for (int c = 0; c < 2; c++){
        int slot = c*256 + tid;
        srowB[c] = slot >> 3;
        scolB[c] = ((slot & 7) ^ (srowB[c] & 7)) * 8;
    }
    for (int k0 = 0; k0 < K; k0 += 64){
        #pragma unroll
        for (int c = 0; c < 4; c++){
            int slot = c*256 + tid;
            size_t so = (size_t)srowA[c]*K + k0 + scolA[c];
            GLOAD_LDS16(Ahp + so, &Ah[0][0] + slot*8);
            if (TERMS == 3) GLOAD_LDS16(Alp + so, &Al[0][0] + slot*8);
        }
        #pragma unroll
        for (int c = 0; c < 2; c++){
            int slot = c*256 + tid;
            size_t so = (size_t)srowB[c]*K + k0 + scolB[c];
            GLOAD_LDS16(Wph + so, &Bh[0][0] + slot*8);
            GLOAD_LDS16(Wpl + so, &Bl[0][0] + slot*8);
        }
        __syncthreads();
        #pragma unroll
        for (int ks = 0; ks < 2; ks++){
            int scg = ((ks*4 + lg) ^ (lm & 7)) * 8;
            short8 ah[4], al[4], bh[2], bl[2];
            #pragma unroll
            for (int mf = 0; mf < 4; mf++){
                ah[mf] = *(const short8*)&Ah[wr*64 + mf*16 + lm][scg];
                if (TERMS == 3) al[mf] = *(const short8*)&Al[wr*64 + mf*16 + lm][scg];
            }
            #pragma unroll
            for (int nf = 0; nf < 2; nf++){
                bh[nf] = *(const short8*)&Bh[wc*32 + nf*16 + lm][scg];
                bl[nf] = *(const short8*)&Bl[wc*32 + nf*16 + lm][scg];
            }
            __builtin_amdgcn_s_setprio(1);
            #pragma unroll
            for (int mf = 0; mf < 4; mf++)
                #pragma unroll
                for (int nf = 0; nf < 2; nf++){
                    acc[mf][nf] = __builtin_amdgcn_mfma_f32_16x16x32_bf16(ah[mf], bh[nf], acc[mf][nf], 0, 0, 0);
                    if (TERMS == 3)
                        acc[mf][nf] = __builtin_amdgcn_mfma_f32_16x16x32_bf16(al[mf], bh[nf], acc[mf][nf], 0, 0, 0);
                    acc[mf][nf] = __builtin_amdgcn_mfma_f32_16x16x32_bf16(ah[mf], bl[nf], acc[mf][nf], 0, 0, 0);
                }
            __builtin_amdgcn_s_setprio(0);
        }
        __syncthreads();
    }
    #pragma unroll
    for (int nf = 0; nf < 2; nf++){
        int col = colBase + wc*32 + nf*16 + lm;
        float bv = bias[col];
        float ssum = 0.f, ssq = 0.f;
        #pragma unroll
        for (int mf = 0; mf < 4; mf++){
            int row = rowBase + wr*64 + mf*16 + lg*4;
            #pragma unroll
            for (int j = 0; j < 4; j++){
                float o = acc[mf][nf][j] + bv;
                if (ACT) o = fmaxf(o, 0.f);
                if (STATS){ ssum += o; ssq += o*o; }
                size_t idx = (size_t)(row + j)*Nout + col;
                if (EPI == 0){
                    ((float*)C0)[idx] = o;
                } else if (EPI == 1){
                    u16 hh = tbf(o);
                    ((u16*)C0)[idx] = hh;
                    ((u16*)C1)[idx] = tbf(o - bf2f(hh));
                } else {
                    ((u16*)C0)[idx] = f2bf(o);
                }
            }
        }
        if (STATS){
            ssum += __shfl_xor(ssum, 16); ssum += __shfl_xor(ssum, 32);
            ssq  += __shfl_xor(ssq, 16);  ssq  += __shfl_xor(ssq, 32);
            if (lg == 0){
                atomicAdd(&stat_sums[col], ssum);
                atomicAdd(&stat_sums[512 + col], ssq);
            }
        }
    }
}

static __device__ inline void xcd_tile(int gx, int gy, int& rowBase, int& colBase){
    int nwg = gx * gy;
    int orig = blockIdx.x + gx*blockIdx.y;
    int q8 = nwg >> 3, r8 = nwg & 7;
    int xcd = orig & 7, pos = orig >> 3;
    int wg = (xcd < r8 ? xcd*(q8+1) : r8*(q8+1) + (xcd - r8)*q8) + pos;
    rowBase = (wg / gx) * 128;
    colBase = (wg % gx) * 64;
}

// standalone GEMM kernel
template<int ACT, int EPI, int TERMS, int STATS>
__global__ __launch_bounds__(256) void gemm_ps(const u16* __restrict__ Ahg,
        const u16* __restrict__ Alg,
        const u16* __restrict__ Wth, const u16* __restrict__ Wtl,
        const float* __restrict__ bias,
        void* __restrict__ C0, void* __restrict__ C1,
        float* __restrict__ stat_sums, int K, int Nout){
    __shared__ __align__(16) char lds[49152];
    int rowBase, colBase;
    xcd_tile(gridDim.x, gridDim.y, rowBase, colBase);
    gemm_body<ACT,EPI,TERMS,STATS>(lds, Ahg, Alg, Wth, Wtl, bias, C0, C1, stat_sums, K, Nout, rowBase, colBase);
}

// triple-merged launch: z=0 GIN-1a, z=1 v GEMM, z=2 M1
__global__ __launch_bounds__(256) void triple_gemm(
        const u16* __restrict__ Gh, const u16* __restrict__ Gl,
        const u16* __restrict__ w1h, const u16* __restrict__ w1l,
        const float* __restrict__ b1, u16* __restrict__ Th, u16* __restrict__ Tl,
        const u16* __restrict__ Xh,
        const u16* __restrict__ wvh, const u16* __restrict__ wvl,
        const float* __restrict__ vb, u16* __restrict__ vbf,
        const u16* __restrict__ sewh, const u16* __restrict__ sewl,
        const u16* __restrict__ wqkh, const u16* __restrict__ wqkl,
        const float* __restrict__ zbias, float* __restrict__ M1){
    __shared__ __align__(16) char lds[49152];
    int z = blockIdx.z;
    if (z <= 1){
        int rowBase, colBase;
        xcd_tile(gridDim.x, gridDim.y, rowBase, colBase);
        if (z == 0)
            gemm_body<1,1,3,0>(lds, Gh, Gl, w1h, w1l, b1, Th, Tl, nullptr, 512, 512, rowBase, colBase);
        else
            gemm_body<0,2,2,0>(lds, Xh, nullptr, wvh, wvl, vb, vbf, nullptr, nullptr, 512, 512, rowBase, colBase);
    } else {
        int orig = blockIdx.x + gridDim.x*blockIdx.y;
        if (orig >= 64) return;
        int rowBase = (orig >> 4) * 128, colBase = (orig & 15) * 64;
        gemm_body<0,0,3,0>(lds, sewh, sewl, wqkh, wqkl, zbias, M1, nullptr, nullptr, 512, 1024, rowBase, colBase);
    }
}

// ---------------- MFMA ragged masked flash attention, 128-row q-blocks ----------------
// Balanced XCD swizzle (round 20) + Q-prescale (exact) + T13 defer-max + stage-first loop.
#define ATS 72
__global__ __launch_bounds__(512) void attn_mfma_kernel(const u16* __restrict__ qkH,
        const u16* __restrict__ qkL, const u16* __restrict__ vbf,
        const u64* __restrict__ maskbits,
        const int* __restrict__ ptr, u16* __restrict__ oh, int N){
    __shared__ u16 Kh[64][ATS];
    __shared__ u16 Kl[64][ATS];
    __shared__ u16 Vt[64][ATS];
    __shared__ u16 Pl[8][16][ATS];
    int orig = blockIdx.x + 4*blockIdx.y + 32*blockIdx.z;
    int xcd = orig & 7, pos = orig >> 3;
    int h  = xcd;                 // one head per XCD: perfectly balanced
    int b  = pos >> 2;            // 32 graphs per XCD
    int q0 = (pos & 3) * 128;     // q-siblings consecutive -> co-XCD K/V reuse
    int base = ptr[b], size = ptr[b+1] - base;
    if (q0 >= size) return;
    int tid = threadIdx.x, w = tid >> 6, l = tid & 63;
    int lg = l >> 4, lm = l & 15;
    int jj = tid & 63, db8 = (tid >> 6)*8;
    short8 qh[2], ql[2];
    {
        int qrow = q0 + w*16 + lm;
        int qr = (qrow < size) ? qrow : 0;
        const u16* qph = qkH + (size_t)(base + qr)*1024 + 512 + h*64;
        const u16* qpl = qkL + (size_t)(base + qr)*1024 + 512 + h*64;
        #pragma unroll
        for (int ks = 0; ks < 2; ks++){
            short8 th = *(const short8*)(qph + ks*32 + lg*8);
            short8 tl = *(const short8*)(qpl + ks*32 + lg*8);
            if (qrow >= size){ th = short8{0,0,0,0,0,0,0,0}; tl = short8{0,0,0,0,0,0,0,0}; }
            // fold softmax scale 1/8 into Q: power-of-2 -> exact in bf16
            #pragma unroll
            for (int i = 0; i < 8; i++){
                ((u16*)&th)[i] = tbf(bf2f(((u16*)&th)[i]) * 0.125f);
                ((u16*)&tl)[i] = tbf(bf2f(((u16*)&tl)[i]) * 0.125f);
            }
            qh[ks] = th; ql[ks] = tl;
        }
    }
    f32x4 acco[4] = {};
    float mrow[4], lrow[4];
    #pragma unroll
    for (int j = 0; j < 4; j++){ mrow[j] = -INFINITY; lrow[j] = 0.f; }
    int nt = (size + 63) >> 6;
    auto STAGE = [&](int t){
        int key = t*64 + jj;
        bool ok = key < size;
        size_t node = (size_t)(base + (ok ? key : 0));
        ushort8 z = {0,0,0,0,0,0,0,0};
        ushort8 kh0 = ok ? *(const ushort8*)(qkH + node*1024 + h*64 + db8) : z;
        ushort8 kl0 = ok ? *(const ushort8*)(qkL + node*1024 + h*64 + db8) : z;
        ushort8 v0  = ok ? *(const ushort8*)(vbf + node*512  + h*64 + db8) : z;
        *(ushort8*)&Kh[jj][db8] = kh0;
        *(ushort8*)&Kl[jj][db8] = kl0;
        #pragma unroll
        for (int i = 0; i < 8; i++) Vt[db8 + i][jj] = v0[i];
    };
    STAGE(0);
    __syncthreads();
    for (int t = 0; t < nt; t++){
        int j0 = t*64;
        f32x4 sc[4] = {};
        __builtin_amdgcn_s_setprio(1);
        #pragma unroll
        for (int nf = 0; nf < 4; nf++)
            #pragma unroll
            for (int ks = 0; ks < 2; ks++){
                short8 kh = *(const short8*)&Kh[nf*16 + lm][ks*32 + lg*8];
                short8 kl = *(const short8*)&Kl[nf*16 + lm][ks*32 + lg*8];
                sc[nf] = __builtin_amdgcn_mfma_f32_16x16x32_bf16(qh[ks], kh, sc[nf], 0, 0, 0);
                sc[nf] = __builtin_amdgcn_mfma_f32_16x16x32_bf16(ql[ks], kh, sc[nf], 0, 0, 0);
                sc[nf] = __builtin_amdgcn_mfma_f32_16x16x32_bf16(qh[ks], kl, sc[nf], 0, 0, 0);
            }
        __builtin_amdgcn_s_setprio(0);
        u64 mb[4];
        #pragma unroll
        for (int j = 0; j < 4; j++)
            mb[j] = maskbits[((size_t)b*LMAX + (q0 + w*16 + lg*4 + j))*8 + t];
        float mx[4], alpha[4];
        #pragma unroll
        for (int j = 0; j < 4; j++){
            float s0 = -INFINITY;
            #pragma unroll
            for (int nf = 0; nf < 4; nf++){
                int key = j0 + nf*16 + lm;
                float s = sc[nf][j];
                bool msk = (key >= size) || ((mb[j] >> (nf*16 + lm)) & 1);
                s = msk ? -INFINITY : s;
                sc[nf][j] = s;
                s0 = fmaxf(s0, s);
            }
            #pragma unroll
            for (int off = 1; off < 16; off <<= 1) s0 = fmaxf(s0, __shfl_xor(s0, off));
            mx[j] = s0;
        }
        // T13 defer-max: only advance running max when it grows by >8.
        // (exact: numerator/denominator of softmax share the factor; P <= e^8 fits bf16)
        #pragma unroll
        for (int j = 0; j < 4; j++){
            if (mx[j] > mrow[j] + 8.f){
                alpha[j] = __expf(mrow[j] - mx[j]);   // exp(-inf)=0 on first finite tile
                mrow[j] = mx[j];
            } else {
                alpha[j] = 1.f;                        // deferred / fully-masked tile
            }
        }
        float ps[4] = {0.f, 0.f, 0.f, 0.f};
        #pragma unroll
        for (int nf = 0; nf < 4; nf++)
            #pragma unroll
            for (int j = 0; j < 4; j++){
                float p = (mrow[j] == -INFINITY) ? 0.f : __expf(sc[nf][j] - mrow[j]);
                ps[j] += p;
                Pl[w][lg*4 + j][nf*16 + lm] = tbf(p);
            }
        #pragma unroll
        for (int j = 0; j < 4; j++){
            float s = ps[j];
            #pragma unroll
            for (int off = 1; off < 16; off <<= 1) s += __shfl_xor(s, off);
            lrow[j] = lrow[j]*alpha[j] + s;
        }
        #pragma unroll
        for (int df = 0; df < 4; df++)
            #pragma unroll
            for (int j = 0; j < 4; j++) acco[df][j] *= alpha[j];
        __builtin_amdgcn_s_setprio(1);
        #pragma unroll
        for (int ks = 0; ks < 2; ks++){
            short8 pf = *(const short8*)&Pl[w][lm][ks*32 + lg*8];
            #pragma unroll
            for (int df = 0; df < 4; df++){
                short8 vf = *(const short8*)&Vt[df*16 + lm][ks*32 + lg*8];
                acco[df] = __builtin_amdgcn_mfma_f32_16x16x32_bf16(pf, vf, acco[df], 0, 0, 0);
            }
        }
        __builtin_amdgcn_s_setprio(0);
        if (t + 1 < nt){
            __syncthreads();      // all waves done reading tile t
            STAGE(t + 1);
            __syncthreads();      // tile t+1 visible
        }
    }
    #pragma unroll
    for (int j = 0; j < 4; j++){
        int r = q0 + w*16 + lg*4 + j;
        if (r < size){
            float inv = 1.f / lrow[j];
            #pragma unroll
            for (int df = 0; df < 4; df++){
                float o = acco[df][j] * inv;
                oh[(size_t)(base + r)*D + h*64 + df*16 + lm] = f2bf(o);
            }
        }
    }
}

extern "C" void kernel_launch(void* const* d_in, const int* in_sizes, int n_in,
                              void* d_out, int out_size, void* d_ws, size_t ws_size,
                              hipStream_t stream){
    const float* x        = (const float*)d_in[0];
    const int*   ei_raw   = (const int*)d_in[1];
    const unsigned char* mask_raw = (const unsigned char*)d_in[2];
    const int*   ptr_raw  = (const int*)d_in[3];
    const float* gin_w1   = (const float*)d_in[4];
    const float* gin_b1   = (const float*)d_in[5];
    const float* gin_w2   = (const float*)d_in[6];
    const float* gin_b2   = (const float*)d_in[7];
    const float* bn_gamma = (const float*)d_in[8];
    const float* bn_beta  = (const float*)d_in[9];
    const float* se_w     = (const float*)d_in[10];
    const float* se_b     = (const float*)d_in[11];
    const float* qk_w     = (const float*)d_in[12];
    const float* qk_b     = (const float*)d_in[13];
    const float* v_w      = (const float*)d_in[14];
    const float* v_b      = (const float*)d_in[15];
    const float* out_w    = (const float*)d_in[16];
    const float* out_b    = (const float*)d_in[17];

    const int N  = in_sizes[0] / D;       // 12160
    const int E  = in_sizes[1] / 2;       // 97280
    const int B  = in_sizes[3] - 1;       // 32
    const int Mn = in_sizes[2];           // B*512*512

    char* ws = (char*)d_ws;
    char* p = ws;
    auto alloc = [&](size_t bytes) -> char* {
        char* q = p; p += (bytes + 255) & ~(size_t)255; return q;
    };
    size_t PLANE = (size_t)N * D * sizeof(u16);
    u16* pairX = (u16*)alloc(2*PLANE);
    u16* pairG = (u16*)alloc(2*PLANE);
    u16* pairT = (u16*)alloc(2*PLANE);
    u16* pairH = (u16*)alloc(2*PLANE);
    u16* v_bf  = (u16*)alloc(PLANE);
    u16* Xh = pairX, *Xl = pairX + (size_t)N*D;
    u16* Gh = pairG, *Gl = pairG + (size_t)N*D;
    u16* Th = pairT, *Tl = pairT + (size_t)N*D;
    u16* Hh = pairH, *Hl = pairH + (size_t)N*D;
    float* sums   = (float*)alloc(1024*sizeof(float));
    int*   flags  = (int*)alloc(16*sizeof(int));
    int*   deg    = (int*)alloc((size_t)N*sizeof(int));
    int*   offs   = (int*)alloc((size_t)(N+1)*sizeof(int));
    int*   cursor = (int*)alloc((size_t)N*sizeof(int));
    int*   in_src = (int*)alloc((size_t)E*sizeof(int));
    int*   ptr32  = (int*)alloc(64*sizeof(int));
    int*   totals = (int*)alloc(64*sizeof(int));
    u64*   mbits  = (u64*)alloc((size_t)(Mn/64)*sizeof(u64));
    u16*   wtsh   = (u16*)alloc((size_t)2883584*sizeof(u16));
    u16*   wtsl   = (u16*)alloc((size_t)2883584*sizeof(u16));
    u16*   sewh   = (u16*)alloc((size_t)D*D*sizeof(u16));
    u16*   sewl   = (u16*)alloc((size_t)D*D*sizeof(u16));
    float* M1     = (float*)alloc((size_t)D*1024*sizeof(float));
    u16*   wbig_h = (u16*)alloc((size_t)1024*D*sizeof(u16));
    u16*   wbig_l = (u16*)alloc((size_t)1024*D*sizeof(u16));
    float* bbig   = (float*)alloc(1024*sizeof(float));
    float* zbias  = (float*)alloc(1024*sizeof(float));
    const size_t SLOT = 262144;
    u16 *wh_v = wtsh, *wl_v = wtsl;
    u16 *wh_g[6], *wl_g[6];
    for (int i = 0; i < 6; i++){ wh_g[i] = wtsh + SLOT*(1+i); wl_g[i] = wtsl + SLOT*(1+i); }
    u16 *wh_qk  = wtsh + SLOT*8,  *wl_qk  = wtsl + SLOT*8;
    u16 *wh_out = wtsh + SLOT*10, *wl_out = wtsl + SLOT*10;

    // --- probe + memsets, mega prologue ---
    probe_mega<<<(N + 255)/256, 256, 0, stream>>>(ptr_raw, mask_raw, flags,
        deg, cursor, sums, zbias, N);
    mega_prologue<<<dim3(32,16,15), 256, 0, stream>>>(
        v_w, gin_w1, gin_w2, se_w, out_w, qk_w, wtsh, wtsl,
        mask_raw, mbits, x, Xh, Xl, sewh, sewl,
        ptr_raw, ptr32, ei_raw, deg, flags, N, E, B, Mn/64);
    int nch = (N + 1023)/1024;
    scanA<<<nch, 1024, 0, stream>>>(deg, offs, totals, N);
    scanB<<<1, 64, 0, stream>>>(totals, nch);
    fill_kernel<<<(E+255)/256, 256, 0, stream>>>(ei_raw, offs, totals, cursor, in_src, flags, E, N);

    dim3 g512(8, N/128), g1024(16, N/128);

    // GIN layer 0: gather, then triple launch {GIN-1a, v GEMM, M1}
    gather_kernel<<<(N+1)/2, 256, 0, stream>>>(Xh, Xl, offs, totals, in_src, Gh, Gl, N);
    triple_gemm<<<dim3(8, N/128, 3), 256, 0, stream>>>(
        Gh, Gl, wh_g[0], wl_g[0], gin_b1, Th, Tl,
        Xh, wh_v, wl_v, v_b, v_bf,
        sewh, sewl, wh_qk, wl_qk, zbias, M1);
    gemm_ps<1,1,3,0><<<g512, 256, 0, stream>>>(Th, Tl, wh_g[1], wl_g[1], gin_b2, Hh, Hl, nullptr, D, D);

    // GIN layers 1..2
    for (int i = 1; i < NGIN; i++){
        gather_kernel<<<(N+1)/2, 256, 0, stream>>>(Hh, Hl, offs, totals, in_src, Gh, Gl, N);
        gemm_ps<1,1,3,0><<<g512, 256, 0, stream>>>(Gh, Gl, wh_g[2*i], wl_g[2*i], gin_b1 + (size_t)i*D, Th, Tl, nullptr, D, D);
        if (i == NGIN - 1)
            gemm_ps<1,1,3,1><<<g512, 256, 0, stream>>>(Th, Tl, wh_g[2*i+1], wl_g[2*i+1], gin_b2 + (size_t)i*D, Hh, Hl, sums, D, D);
        else
            gemm_ps<1,1,3,0><<<g512, 256, 0, stream>>>(Th, Tl, wh_g[2*i+1], wl_g[2*i+1], gin_b2 + (size_t)i*D, Hh, Hl, nullptr, D, D);
    }

    // fold BN + se into qk weight
    fold_mega<<<dim3(32,16,2), 256, 0, stream>>>(M1, sums, bn_gamma, bn_beta,
        se_b, qk_w, qk_b, wbig_h, wbig_l, bbig, N);

    // qk = gin_out @ Wbig + bbig -> hi plane = pairX (N x 1024), lo plane = pairG
    gemm_ps<0,1,3,0><<<g1024, 256, 0, stream>>>(Hh, Hl, wbig_h, wbig_l, bbig, pairX, pairG, nullptr, D, 2*D);

    // attention: split qk + bf16 v -> plain bf16 output in Th
    attn_mfma_kernel<<<dim3(LMAX/128, NHEAD, B), 512, 0, stream>>>(pairX, pairG, v_bf, mbits, ptr32, Th, N);

    // out = attn_out @ out_w + out_b -> f32 d_out (2-term)
    gemm_ps<0,0,2,0><<<g512, 256, 0, stream>>>(Th, nullptr, wh_out, wl_out, out_b, (float*)d_out, nullptr, nullptr, D, D);
}

// Round 22
// 473.486 us; speedup vs baseline: 1.0535x; 1.0091x over previous
//
#include <hip/hip_runtime.h>
#include <hip/hip_bf16.h>
#include <cstdint>
#include <cstddef>

#define D 512
#define NHEAD 8
#define LMAX 512
#define NGIN 3

typedef unsigned short u16;
typedef unsigned long long u64;
typedef __attribute__((ext_vector_type(8))) short short8;
typedef __attribute__((ext_vector_type(8))) unsigned short ushort8;
typedef __attribute__((ext_vector_type(4))) unsigned short us4;
typedef __attribute__((ext_vector_type(4))) float f32x4;

static __device__ inline u16 f2bf(float f){
    union { float f; uint32_t u; } c; c.f = f;
    uint32_t r = (c.u + 0x7fffu + ((c.u >> 16) & 1u)) >> 16;
    return (u16)r;
}
static __device__ inline u16 tbf(float f){
    union { float f; uint32_t u; } c; c.f = f;
    return (u16)(c.u >> 16);
}
static __device__ inline float bf2f(u16 h){
    union { uint32_t u; float f; } c; c.u = ((uint32_t)h) << 16; return c.f;
}

#define GLOAD_LDS16(SRC, DST) \
    __builtin_amdgcn_global_load_lds( \
        (const __attribute__((address_space(1))) void*)(SRC), \
        (__attribute__((address_space(3))) void*)(DST), 16, 0, 0)

// ---------------- probe + memsets (one launch) ----------------
__global__ __launch_bounds__(256) void probe_mega(const int* __restrict__ ptr_raw,
        const unsigned char* __restrict__ mask_raw, int* __restrict__ flags,
        int* __restrict__ deg, int* __restrict__ cursor,
        float* __restrict__ sums, float* __restrict__ zbias, int N){
    int i = blockIdx.x*256 + threadIdx.x;
    if (i < N){ deg[i] = 0; cursor[i] = 0; }
    if (i < 1024){ sums[i] = 0.f; zbias[i] = 0.f; }
    if (blockIdx.x == 0 && threadIdx.x == 0){
        flags[0] = (ptr_raw[1] == 0) ? 1 : 0;
        int cntOdd = 0, cnt4 = 0;
        for (int k = 1; k < 2048; k += 2) cntOdd += (mask_raw[k] != 0);
        for (int k = 4; k < 2048; k += 8) cnt4   += (mask_raw[k] != 0);
        flags[1] = (cntOdd > 64) ? 1 : ((cnt4 > 16) ? 4 : 8);
    }
}

// ---------------- mega prologue: z-roles ----------------
__global__ __launch_bounds__(256) void mega_prologue(
        const float* __restrict__ v_w, const float* __restrict__ gin_w1,
        const float* __restrict__ gin_w2, const float* __restrict__ se_w,
        const float* __restrict__ out_w, const float* __restrict__ qk_w,
        u16* __restrict__ wtsh, u16* __restrict__ wtsl,
        const unsigned char* __restrict__ mask_raw, u64* __restrict__ mbits,
        const float* __restrict__ x, u16* __restrict__ Xh, u16* __restrict__ Xl,
        u16* __restrict__ sewh, u16* __restrict__ sewl,
        const int* __restrict__ ptr_raw, int* __restrict__ ptr32,
        const int* __restrict__ ei_raw, int* __restrict__ deg,
        const int* __restrict__ flags,
        int Nnodes, int E, int B, int Mn64){
    int z = blockIdx.z;
    int bid = blockIdx.y*32 + blockIdx.x;
    int tid = threadIdx.x;
    if (z <= 9){
        int Nout = (z == 9) ? 1024 : 512;
        if (z < 9 && blockIdx.x >= 16) return;
        const size_t SLOT = 262144;
        const float* W; int slot;
        switch (z){
            case 0: W = v_w; slot = 0; break;
            case 1: W = gin_w1;          slot = 1; break;
            case 2: W = gin_w2;          slot = 2; break;
            case 3: W = gin_w1 + 262144; slot = 3; break;
            case 4: W = gin_w2 + 262144; slot = 4; break;
            case 5: W = gin_w1 + 524288; slot = 5; break;
            case 6: W = gin_w2 + 524288; slot = 6; break;
            case 7: W = se_w;  slot = 7; break;
            case 8: W = out_w; slot = 10; break;
            default: W = qk_w; slot = 8; break;
        }
        u16* Wh = wtsh + SLOT*slot;
        u16* Wl = wtsl + SLOT*slot;
        __shared__ float T[32][33];
        int nb = blockIdx.x*32, kb = blockIdx.y*32;
        int ln = tid & 31, lk = tid >> 5;
        #pragma unroll
        for (int i = 0; i < 4; i++)
            T[lk + 8*i][ln] = W[(size_t)(kb + lk + 8*i)*Nout + nb + ln];
        __syncthreads();
        #pragma unroll
        for (int i = 0; i < 4; i++){
            float val = T[ln][lk + 8*i];
            u16 h = tbf(val);
            size_t idx = (size_t)(nb + lk + 8*i)*512 + kb + ln;
            Wh[idx] = h;
            Wl[idx] = tbf(val - bf2f(h));
        }
    } else if (z == 10){
        int idx = bid*256 + tid;
        if (idx >= Mn64) return;
        int w = flags[1];
        size_t ebase = (size_t)(idx >> 3) * 512 + (size_t)(idx & 7) * 64;
        u64 bits = 0;
        if (w == 1){
            const u64* p8 = (const u64*)(mask_raw + ebase);
            #pragma unroll
            for (int g = 0; g < 8; g++){
                u64 v = p8[g];
                #pragma unroll
                for (int by = 0; by < 8; by++)
                    if ((v >> (by*8)) & 0xffull) bits |= 1ull << (g*8 + by);
            }
        } else {
            for (int j = 0; j < 64; j++)
                if (mask_raw[(ebase + j) * (size_t)w]) bits |= 1ull << j;
        }
        mbits[idx] = bits;
    } else if (z == 11){
        int total4 = Nnodes*D/4;
        for (int i = bid*256 + tid; i < total4; i += 131072){
            float4 v = *(const float4*)(x + (size_t)i*4);
            float fv[4] = {v.x, v.y, v.z, v.w};
            us4 h4, l4;
            #pragma unroll
            for (int j = 0; j < 4; j++){
                u16 hh = tbf(fv[j]);
                h4[j] = hh;
                l4[j] = tbf(fv[j] - bf2f(hh));
            }
            *(us4*)(Xh + (size_t)i*4) = h4;
            *(us4*)(Xl + (size_t)i*4) = l4;
        }
    } else if (z == 12){
        int i = bid*256 + tid;
        if (i >= D*D/4) return;
        float4 v = *(const float4*)(se_w + (size_t)i*4);
        float fv[4] = {v.x, v.y, v.z, v.w};
        us4 h4, l4;
        #pragma unroll
        for (int j = 0; j < 4; j++){
            u16 hh = tbf(fv[j]);
            h4[j] = hh;
            l4[j] = tbf(fv[j] - bf2f(hh));
        }
        *(us4*)(sewh + (size_t)i*4) = h4;
        *(us4*)(sewl + (size_t)i*4) = l4;
    } else if (z == 13){
        if (bid == 0 && tid <= B)
            ptr32[tid] = flags[0] ? ptr_raw[2*tid] : ptr_raw[tid];
    } else {
        int e = bid*256 + tid;
        if (e < E){
            int d = flags[0] ? ei_raw[2*(E + e)] : ei_raw[E + e];
            if ((unsigned)d < (unsigned)Nnodes) atomicAdd(&deg[d], 1);
        }
    }
}

// ---------------- parallel scan: A (local) / B (bases); base-add folded into consumers ----------------
__global__ __launch_bounds__(1024) void scanA(const int* __restrict__ deg,
        int* __restrict__ offs, int* __restrict__ totals, int n){
    __shared__ int wsum[16];
    int ch = blockIdx.x;
    int tid = threadIdx.x, lane = tid & 63, wv = tid >> 6;
    int i = ch*1024 + tid;
    int val = (i < n) ? deg[i] : 0;
    int s = val;
    #pragma unroll
    for (int off = 1; off < 64; off <<= 1){
        int t = __shfl_up(s, off);
        if (lane >= off) s += t;
    }
    if (lane == 63) wsum[wv] = s;
    __syncthreads();
    if (wv == 0){
        int t = (lane < 16) ? wsum[lane] : 0;
        #pragma unroll
        for (int off = 1; off < 16; off <<= 1){
            int u = __shfl_up(t, off);
            if (lane >= off) t += u;
        }
        if (lane < 16) wsum[lane] = t;
    }
    __syncthreads();
    int wbase = wv ? wsum[wv-1] : 0;
    if (i < n) offs[i+1] = wbase + s;
    if (tid == 1023) totals[ch] = wsum[15];
    if (ch == 0 && tid == 0) offs[0] = 0;
}

__global__ void scanB(int* __restrict__ totals, int nch){
    int lane = threadIdx.x;
    int v = (lane < nch) ? totals[lane] : 0;
    int s = v;
    #pragma unroll
    for (int off = 1; off < 64; off <<= 1){
        int t = __shfl_up(s, off);
        if (lane >= off) s += t;
    }
    if (lane < nch) totals[lane] = s - v;   // exclusive chunk base
}

// offs_final[i] = offs[i] + (i>=1 ? totals[(i-1)>>10] : 0)
__global__ void fill_kernel(const int* __restrict__ ei_raw, const int* __restrict__ offs,
                            const int* __restrict__ totals,
                            int* __restrict__ cursor, int* __restrict__ in_src,
                            const int* __restrict__ flags, int E, int N){
    int e = blockIdx.x*256 + threadIdx.x;
    if (e < E){
        int d = flags[0] ? ei_raw[2*(E + e)] : ei_raw[E + e];
        if ((unsigned)d < (unsigned)N){
            int slot = atomicAdd(&cursor[d], 1);
            int start = offs[d] + (d ? totals[(d-1) >> 10] : 0);
            in_src[start + slot] = flags[0] ? ei_raw[2*e] : ei_raw[e];
        }
    }
}

// ---------------- gather (ushort8 vectorized, 4 nodes/block; bit-identical math) ----------------
__global__ __launch_bounds__(256) void gather_kernel(const u16* __restrict__ hh,
        const u16* __restrict__ hl,
        const int* __restrict__ offs, const int* __restrict__ totals,
        const int* __restrict__ in_src,
        u16* __restrict__ oh, u16* __restrict__ ol, int N){
    int node = blockIdx.x*4 + (threadIdx.x >> 6);
    if (node >= N) return;
    int t = threadIdx.x & 63;
    size_t rb = (size_t)node*D + t*8;
    ushort8 vh = *(const ushort8*)(hh + rb);
    ushort8 vl = *(const ushort8*)(hl + rb);
    float a[8];
    #pragma unroll
    for (int j = 0; j < 8; j++) a[j] = bf2f(vh[j]) + bf2f(vl[j]);
    int s = offs[node] + (node ? totals[(node-1) >> 10] : 0);
    int e = offs[node+1] + totals[node >> 10];
    for (int i = s; i < e; i++){
        size_t sb = (size_t)in_src[i]*D + t*8;
        ushort8 nh = *(const ushort8*)(hh + sb);
        ushort8 nl = *(const ushort8*)(hl + sb);
        #pragma unroll
        for (int j = 0; j < 8; j++) a[j] += bf2f(nh[j]) + bf2f(nl[j]);
    }
    ushort8 h8, l8;
    #pragma unroll
    for (int j = 0; j < 8; j++){
        u16 hh2 = tbf(a[j]);
        h8[j] = hh2;
        l8[j] = tbf(a[j] - bf2f(hh2));
    }
    *(ushort8*)(oh + rb) = h8;
    *(ushort8*)(ol + rb) = l8;
}

// ---------------- fold mega ----------------
__global__ __launch_bounds__(256) void fold_mega(const float* __restrict__ M1,
        const float* __restrict__ sums, const float* __restrict__ gamma,
        const float* __restrict__ beta,
        const float* __restrict__ se_b, const float* __restrict__ qk_w,
        const float* __restrict__ qk_b,
        u16* __restrict__ Wh, u16* __restrict__ Wl, float* __restrict__ bbig, int n){
    float inv_n = 1.f / (float)n;
    if (blockIdx.z == 0){
        __shared__ float T[32][33];
        int nb = blockIdx.x*32, kb = blockIdx.y*32;
        int ln = threadIdx.x & 31, lk = threadIdx.x >> 5;
        #pragma unroll
        for (int i = 0; i < 4; i++){
            int k = kb + lk + 8*i;
            float mean = sums[k] * inv_n;
            float var = sums[512+k] * inv_n - mean*mean;
            float scale = rsqrtf(var + 1e-5f) * gamma[k];
            T[lk + 8*i][ln] = M1[(size_t)k*1024 + nb + ln] * scale;
        }
        __syncthreads();
        #pragma unroll
        for (int i = 0; i < 4; i++){
            float val = T[ln][lk + 8*i];
            u16 h = tbf(val);
            size_t idx = (size_t)(nb + lk + 8*i)*512 + kb + ln;
            Wh[idx] = h;
            Wl[idx] = tbf(val - bf2f(h));
        }
    } else {
        int wv = threadIdx.x >> 6, lane = threadIdx.x & 63;
        if (wv >= 2) return;
        int nidx = (blockIdx.y*32 + blockIdx.x)*2 + wv;
        float acc = 0.f;
        for (int k = lane; k < 512; k += 64){
            float mean = sums[k] * inv_n;
            float var = sums[512+k] * inv_n - mean*mean;
            float scale = rsqrtf(var + 1e-5f) * gamma[k];
            float shift = beta[k] - mean*scale;
            acc += shift*M1[(size_t)k*1024 + nidx] + se_b[k]*qk_w[(size_t)k*1024 + nidx];
        }
        #pragma unroll
        for (int off = 32; off > 0; off >>= 1) acc += __shfl_xor(acc, off);
        if (lane == 0) bbig[nidx] = acc + qk_b[nidx];
    }
}

// ---------------- shared GEMM body: 128x64 tile, 256 thr, 48KB LDS arena ----------------
template<int ACT, int EPI, int TERMS, int STATS>
__device__ __forceinline__ void gemm_body(char* ldsbase,
        const u16* __restrict__ Ahg, const u16* __restrict__ Alg,
        const u16* __restrict__ Wth, const u16* __restrict__ Wtl,
        const float* __restrict__ bias,
        void* __restrict__ C0, void* __restrict__ C1,
        float* __restrict__ stat_sums, int K, int Nout, int rowBase, int colBase){
    u16 (*Ah)[64] = (u16(*)[64])(ldsbase);
    u16 (*Al)[64] = (u16(*)[64])(ldsbase + 16384);
    u16 (*Bh)[64] = (u16(*)[64])(ldsbase + 32768);
    u16 (*Bl)[64] = (u16(*)[64])(ldsbase + 40960);
    int tid = threadIdx.x;
    int w = tid >> 6, l = tid & 63, lg = l >> 4, lm = l & 15;
    int wr = w >> 1, wc = w & 1;
    f32x4 acc[4][2] = {};
    const u16* Ahp = Ahg + (size_t)rowBase*K;
    const u16* Alp = (TERMS == 3) ? Alg + (size_t)rowBase*K : nullptr;
    const u16* Wph = Wth + (size_t)colBase*K;
    const u16* Wpl = Wtl + (size_t)colBase*K;
    int srowA[4], scolA[4], srowB[2], scolB[2];
    #pragma unroll
    for (int c = 0; c < 4; c++){
        int slot = c*256 + tid;
        srowA[c] = slot >> 3;
        scolA[c] = ((slot & 7) ^ (srowA[c] & 7)) * 8;
    }
    #pragma unroll
    for (int c = 0; c < 2; c++){
        int slot = c*256 + tid;
        srowB[c] = slot >> 3;
        scolB[c] = ((slot & 7) ^ (srowB[c] & 7)) * 8;
    }
    for (int k0 = 0; k0 < K; k0 += 64){
        #pragma unroll
        for (int c = 0; c < 4; c++){
            int slot = c*256 + tid;
            size_t so = (size_t)srowA[c]*K + k0 + scolA[c];
            GLOAD_LDS16(Ahp + so, &Ah[0][0] + slot*8);
            if (TERMS == 3) GLOAD_LDS16(Alp + so, &Al[0][0] + slot*8);
        }
        #pragma unroll
        for (int c = 0; c < 2; c++){
            int slot = c*256 + tid;
            size_t so = (size_t)srowB[c]*K + k0 + scolB[c];
            GLOAD_LDS16(Wph + so, &Bh[0][0] + slot*8);
            GLOAD_LDS16(Wpl + so, &Bl[0][0] + slot*8);
        }
        __syncthreads();
        #pragma unroll
        for (int ks = 0; ks < 2; ks++){
            int scg = ((ks*4 + lg) ^ (lm & 7)) * 8;
            short8 ah[4], al[4], bh[2], bl[2];
            #pragma unroll
            for (int mf = 0; mf < 4; mf++){
                ah[mf] = *(const short8*)&Ah[wr*64 + mf*16 + lm][scg];
                if (TERMS == 3) al[mf] = *(const short8*)&Al[wr*64 + mf*16 + lm][scg];
            }
            #pragma unroll
            for (int nf = 0; nf < 2; nf++){
                bh[nf] = *(const short8*)&Bh[wc*32 + nf*16 + lm][scg];
                bl[nf] = *(const short8*)&Bl[wc*32 + nf*16 + lm][scg];
            }
            __builtin_amdgcn_s_setprio(1);
            #pragma unroll
            for (int mf = 0; mf < 4; mf++)
                #pragma unroll
                for (int nf = 0; nf < 2; nf++){
                    acc[mf][nf] = __builtin_amdgcn_mfma_f32_16x16x32_bf16(ah[mf], bh[nf], acc[mf][nf], 0, 0, 0);
                    if (TERMS == 3)
                        acc[mf][nf] = __builtin_amdgcn_mfma_f32_16x16x32_bf16(al[mf], bh[nf], acc[mf][nf], 0, 0, 0);
                    acc[mf][nf] = __builtin_amdgcn_mfma_f32_16x16x32_bf16(ah[mf], bl[nf], acc[mf][nf], 0, 0, 0);
                }
            __builtin_amdgcn_s_setprio(0);
        }
        __syncthreads();
    }
    #pragma unroll
    for (int nf = 0; nf < 2; nf++){
        int col = colBase + wc*32 + nf*16 + lm;
        float bv = bias[col];
        float ssum = 0.f, ssq = 0.f;
        #pragma unroll
        for (int mf = 0; mf < 4; mf++){
            int row = rowBase + wr*64 + mf*16 + lg*4;
            #pragma unroll
            for (int j = 0; j < 4; j++){
                float o = acc[mf][nf][j] + bv;
                if (ACT) o = fmaxf(o, 0.f);
                if (STATS){ ssum += o; ssq += o*o; }
                size_t idx = (size_t)(row + j)*Nout + col;
                if (EPI == 0){
                    ((float*)C0)[idx] = o;
                } else if (EPI == 1){
                    u16 hh = tbf(o);
                    ((u16*)C0)[idx] = hh;
                    ((u16*)C1)[idx] = tbf(o - bf2f(hh));
                } else {
                    ((u16*)C0)[idx] = f2bf(o);
                }
            }
        }
        if (STATS){
            ssum += __shfl_xor(ssum, 16); ssum += __shfl_xor(ssum, 32);
            ssq  += __shfl_xor(ssq, 16);  ssq  += __shfl_xor(ssq, 32);
            if (lg == 0){
                atomicAdd(&stat_sums[col], ssum);
                atomicAdd(&stat_sums[512 + col], ssq);
            }
        }
    }
}

static __device__ inline void xcd_tile(int gx, int gy, int& rowBase, int& colBase){
    int nwg = gx * gy;
    int orig = blockIdx.x + gx*blockIdx.y;
    int q8 = nwg >> 3, r8 = nwg & 7;
    int xcd = orig & 7, pos = orig >> 3;
    int wg = (xcd < r8 ? xcd*(q8+1) : r8*(q8+1) + (xcd - r8)*q8) + pos;
    rowBase = (wg / gx) * 128;
    colBase = (wg % gx) * 64;
}

// standalone GEMM kernel
template<int ACT, int EPI, int TERMS, int STATS>
__global__ __launch_bounds__(256) void gemm_ps(const u16* __restrict__ Ahg,
        const u16* __restrict__ Alg,
        const u16* __restrict__ Wth, const u16* __restrict__ Wtl,
        const float* __restrict__ bias,
        void* __restrict__ C0, void* __restrict__ C1,
        float* __restrict__ stat_sums, int K, int Nout){
    __shared__ __align__(16) char lds[49152];
    int rowBase, colBase;
    xcd_tile(gridDim.x, gridDim.y, rowBase, colBase);
    gemm_body<ACT,EPI,TERMS,STATS>(lds, Ahg, Alg, Wth, Wtl, bias, C0, C1, stat_sums, K, Nout, rowBase, colBase);
}

// triple-merged launch: z=0 GIN-1a, z=1 v GEMM, z=2 M1
__global__ __launch_bounds__(256) void triple_gemm(
        const u16* __restrict__ Gh, const u16* __restrict__ Gl,
        const u16* __restrict__ w1h, const u16* __restrict__ w1l,
        const float* __restrict__ b1, u16* __restrict__ Th, u16* __restrict__ Tl,
        const u16* __restrict__ Xh,
        const u16* __restrict__ wvh, const u16* __restrict__ wvl,
        const float* __restrict__ vb, u16* __restrict__ vbf,
        const u16* __restrict__ sewh, const u16* __restrict__ sewl,
        const u16* __restrict__ wqkh, const u16* __restrict__ wqkl,
        const float* __restrict__ zbias, float* __restrict__ M1){
    __shared__ __align__(16) char lds[49152];
    int z = blockIdx.z;
    if (z <= 1){
        int rowBase, colBase;
        xcd_tile(gridDim.x, gridDim.y, rowBase, colBase);
        if (z == 0)
            gemm_body<1,1,3,0>(lds, Gh, Gl, w1h, w1l, b1, Th, Tl, nullptr, 512, 512, rowBase, colBase);
        else
            gemm_body<0,2,2,0>(lds, Xh, nullptr, wvh, wvl, vb, vbf, nullptr, nullptr, 512, 512, rowBase, colBase);
    } else {
        int orig = blockIdx.x + gridDim.x*blockIdx.y;
        if (orig >= 64) return;
        int rowBase = (orig >> 4) * 128, colBase = (orig & 15) * 64;
        gemm_body<0,0,3,0>(lds, sewh, sewl, wqkh, wqkl, zbias, M1, nullptr, nullptr, 512, 1024, rowBase, colBase);
    }
}

// ---------------- MFMA ragged masked flash attention, 128-row q-blocks ----------------
// Balanced XCD swizzle + Q-prescale (exact) + T13 defer-max + stage-first loop (round-21-proven).
#define ATS 72
__global__ __launch_bounds__(512) void attn_mfma_kernel(const u16* __restrict__ qkH,
        const u16* __restrict__ qkL, const u16* __restrict__ vbf,
        const u64* __restrict__ maskbits,
        const int* __restrict__ ptr, u16* __restrict__ oh, int N){
    __shared__ u16 Kh[64][ATS];
    __shared__ u16 Kl[64][ATS];
    __shared__ u16 Vt[64][ATS];
    __shared__ u16 Pl[8][16][ATS];
    int orig = blockIdx.x + 4*blockIdx.y + 32*blockIdx.z;
    int xcd = orig & 7, pos = orig >> 3;
    int h  = xcd;
    int b  = pos >> 2;
    int q0 = (pos & 3) * 128;
    int base = ptr[b], size = ptr[b+1] - base;
    if (q0 >= size) return;
    int tid = threadIdx.x, w = tid >> 6, l = tid & 63;
    int lg = l >> 4, lm = l & 15;
    int jj = tid & 63, db8 = (tid >> 6)*8;
    short8 qh[2], ql[2];
    {
        int qrow = q0 + w*16 + lm;
        int qr = (qrow < size) ? qrow : 0;
        const u16* qph = qkH + (size_t)(base + qr)*1024 + 512 + h*64;
        const u16* qpl = qkL + (size_t)(base + qr)*1024 + 512 + h*64;
        #pragma unroll
        for (int ks = 0; ks < 2; ks++){
            short8 th = *(const short8*)(qph + ks*32 + lg*8);
            short8 tl = *(const short8*)(qpl + ks*32 + lg*8);
            if (qrow >= size){ th = short8{0,0,0,0,0,0,0,0}; tl = short8{0,0,0,0,0,0,0,0}; }
            #pragma unroll
            for (int i = 0; i < 8; i++){
                ((u16*)&th)[i] = tbf(bf2f(((u16*)&th)[i]) * 0.125f);
                ((u16*)&tl)[i] = tbf(bf2f(((u16*)&tl)[i]) * 0.125f);
            }
            qh[ks] = th; ql[ks] = tl;
        }
    }
    f32x4 acco[4] = {};
    float mrow[4], lrow[4];
    #pragma unroll
    for (int j = 0; j < 4; j++){ mrow[j] = -INFINITY; lrow[j] = 0.f; }
    int nt = (size + 63) >> 6;
    auto STAGE = [&](int t){
        int key = t*64 + jj;
        bool ok = key < size;
        size_t node = (size_t)(base + (ok ? key : 0));
        ushort8 z = {0,0,0,0,0,0,0,0};
        ushort8 kh0 = ok ? *(const ushort8*)(qkH + node*1024 + h*64 + db8) : z;
        ushort8 kl0 = ok ? *(const ushort8*)(qkL + node*1024 + h*64 + db8) : z;
        ushort8 v0  = ok ? *(const ushort8*)(vbf + node*512  + h*64 + db8) : z;
        *(ushort8*)&Kh[jj][db8] = kh0;
        *(ushort8*)&Kl[jj][db8] = kl0;
        #pragma unroll
        for (int i = 0; i < 8; i++) Vt[db8 + i][jj] = v0[i];
    };
    STAGE(0);
    __syncthreads();
    for (int t = 0; t < nt; t++){
        int j0 = t*64;
        f32x4 sc[4] = {};
        __builtin_amdgcn_s_setprio(1);
        #pragma unroll
        for (int nf = 0; nf < 4; nf++)
            #pragma unroll
            for (int ks = 0; ks < 2; ks++){
                short8 kh = *(const short8*)&Kh[nf*16 + lm][ks*32 + lg*8];
                short8 kl = *(const short8*)&Kl[nf*16 + lm][ks*32 + lg*8];
                sc[nf] = __builtin_amdgcn_mfma_f32_16x16x32_bf16(qh[ks], kh, sc[nf], 0, 0, 0);
                sc[nf] = __builtin_amdgcn_mfma_f32_16x16x32_bf16(ql[ks], kh, sc[nf], 0, 0, 0);
                sc[nf] = __builtin_amdgcn_mfma_f32_16x16x32_bf16(qh[ks], kl, sc[nf], 0, 0, 0);
            }
        __builtin_amdgcn_s_setprio(0);
        u64 mb[4];
        #pragma unroll
        for (int j = 0; j < 4; j++)
            mb[j] = maskbits[((size_t)b*LMAX + (q0 + w*16 + lg*4 + j))*8 + t];
        float mx[4], alpha[4];
        #pragma unroll
        for (int j = 0; j < 4; j++){
            float s0 = -INFINITY;
            #pragma unroll
            for (int nf = 0; nf < 4; nf++){
                int key = j0 + nf*16 + lm;
                float s = sc[nf][j];
                bool msk = (key >= size) || ((mb[j] >> (nf*16 + lm)) & 1);
                s = msk ? -INFINITY : s;
                sc[nf][j] = s;
                s0 = fmaxf(s0, s);
            }
            #pragma unroll
            for (int off = 1; off < 16; off <<= 1) s0 = fmaxf(s0, __shfl_xor(s0, off));
            mx[j] = s0;
        }
        #pragma unroll
        for (int j = 0; j < 4; j++){
            if (mx[j] > mrow[j] + 8.f){
                alpha[j] = __expf(mrow[j] - mx[j]);
                mrow[j] = mx[j];
            } else {
                alpha[j] = 1.f;
            }
        }
        float ps[4] = {0.f, 0.f, 0.f, 0.f};
        #pragma unroll
        for (int nf = 0; nf < 4; nf++)
            #pragma unroll
            for (int j = 0; j < 4; j++){
                float p = (mrow[j] == -INFINITY) ? 0.f : __expf(sc[nf][j] - mrow[j]);
                ps[j] += p;
                Pl[w][lg*4 + j][nf*16 + lm] = tbf(p);
            }
        #pragma unroll
        for (int j = 0; j < 4; j++){
            float s = ps[j];
            #pragma unroll
            for (int off = 1; off < 16; off <<= 1) s += __shfl_xor(s, off);
            lrow[j] = lrow[j]*alpha[j] + s;
        }
        #pragma unroll
        for (int df = 0; df < 4; df++)
            #pragma unroll
            for (int j = 0; j < 4; j++) acco[df][j] *= alpha[j];
        __builtin_amdgcn_s_setprio(1);
        #pragma unroll
        for (int ks = 0; ks < 2; ks++){
            short8 pf = *(const short8*)&Pl[w][lm][ks*32 + lg*8];
            #pragma unroll
            for (int df = 0; df < 4; df++){
                short8 vf = *(const short8*)&Vt[df*16 + lm][ks*32 + lg*8];
                acco[df] = __builtin_amdgcn_mfma_f32_16x16x32_bf16(pf, vf, acco[df], 0, 0, 0);
            }
        }
        __builtin_amdgcn_s_setprio(0);
        if (t + 1 < nt){
            __syncthreads();
            STAGE(t + 1);
            __syncthreads();
        }
    }
    #pragma unroll
    for (int j = 0; j < 4; j++){
        int r = q0 + w*16 + lg*4 + j;
        if (r < size){
            float inv = 1.f / lrow[j];
            #pragma unroll
            for (int df = 0; df < 4; df++){
                float o = acco[df][j] * inv;
                oh[(size_t)(base + r)*D + h*64 + df*16 + lm] = f2bf(o);
            }
        }
    }
}

extern "C" void kernel_launch(void* const* d_in, const int* in_sizes, int n_in,
                              void* d_out, int out_size, void* d_ws, size_t ws_size,
                              hipStream_t stream){
    const float* x        = (const float*)d_in[0];
    const int*   ei_raw   = (const int*)d_in[1];
    const unsigned char* mask_raw = (const unsigned char*)d_in[2];
    const int*   ptr_raw  = (const int*)d_in[3];
    const float* gin_w1   = (const float*)d_in[4];
    const float* gin_b1   = (const float*)d_in[5];
    const float* gin_w2   = (const float*)d_in[6];
    const float* gin_b2   = (const float*)d_in[7];
    const float* bn_gamma = (const float*)d_in[8];
    const float* bn_beta  = (const float*)d_in[9];
    const float* se_w     = (const float*)d_in[10];
    const float* se_b     = (const float*)d_in[11];
    const float* qk_w     = (const float*)d_in[12];
    const float* qk_b     = (const float*)d_in[13];
    const float* v_w      = (const float*)d_in[14];
    const float* v_b      = (const float*)d_in[15];
    const float* out_w    = (const float*)d_in[16];
    const float* out_b    = (const float*)d_in[17];

    const int N  = in_sizes[0] / D;       // 12160
    const int E  = in_sizes[1] / 2;       // 97280
    const int B  = in_sizes[3] - 1;       // 32
    const int Mn = in_sizes[2];           // B*512*512

    char* ws = (char*)d_ws;
    char* p = ws;
    auto alloc = [&](size_t bytes) -> char* {
        char* q = p; p += (bytes + 255) & ~(size_t)255; return q;
    };
    size_t PLANE = (size_t)N * D * sizeof(u16);
    u16* pairX = (u16*)alloc(2*PLANE);
    u16* pairG = (u16*)alloc(2*PLANE);
    u16* pairT = (u16*)alloc(2*PLANE);
    u16* pairH = (u16*)alloc(2*PLANE);
    u16* v_bf  = (u16*)alloc(PLANE);
    u16* Xh = pairX, *Xl = pairX + (size_t)N*D;
    u16* Gh = pairG, *Gl = pairG + (size_t)N*D;
    u16* Th = pairT, *Tl = pairT + (size_t)N*D;
    u16* Hh = pairH, *Hl = pairH + (size_t)N*D;
    float* sums   = (float*)alloc(1024*sizeof(float));
    int*   flags  = (int*)alloc(16*sizeof(int));
    int*   deg    = (int*)alloc((size_t)N*sizeof(int));
    int*   offs   = (int*)alloc((size_t)(N+1)*sizeof(int));
    int*   cursor = (int*)alloc((size_t)N*sizeof(int));
    int*   in_src = (int*)alloc((size_t)E*sizeof(int));
    int*   ptr32  = (int*)alloc(64*sizeof(int));
    int*   totals = (int*)alloc(64*sizeof(int));
    u64*   mbits  = (u64*)alloc((size_t)(Mn/64)*sizeof(u64));
    u16*   wtsh   = (u16*)alloc((size_t)2883584*sizeof(u16));
    u16*   wtsl   = (u16*)alloc((size_t)2883584*sizeof(u16));
    u16*   sewh   = (u16*)alloc((size_t)D*D*sizeof(u16));
    u16*   sewl   = (u16*)alloc((size_t)D*D*sizeof(u16));
    float* M1     = (float*)alloc((size_t)D*1024*sizeof(float));
    u16*   wbig_h = (u16*)alloc((size_t)1024*D*sizeof(u16));
    u16*   wbig_l = (u16*)alloc((size_t)1024*D*sizeof(u16));
    float* bbig   = (float*)alloc(1024*sizeof(float));
    float* zbias  = (float*)alloc(1024*sizeof(float));
    const size_t SLOT = 262144;
    u16 *wh_v = wtsh, *wl_v = wtsl;
    u16 *wh_g[6], *wl_g[6];
    for (int i = 0; i < 6; i++){ wh_g[i] = wtsh + SLOT*(1+i); wl_g[i] = wtsl + SLOT*(1+i); }
    u16 *wh_qk  = wtsh + SLOT*8,  *wl_qk  = wtsl + SLOT*8;
    u16 *wh_out = wtsh + SLOT*10, *wl_out = wtsl + SLOT*10;

    // --- probe + memsets, mega prologue ---
    probe_mega<<<(N + 255)/256, 256, 0, stream>>>(ptr_raw, mask_raw, flags,
        deg, cursor, sums, zbias, N);
    mega_prologue<<<dim3(32,16,15), 256, 0, stream>>>(
        v_w, gin_w1, gin_w2, se_w, out_w, qk_w, wtsh, wtsl,
        mask_raw, mbits, x, Xh, Xl, sewh, sewl,
        ptr_raw, ptr32, ei_raw, deg, flags, N, E, B, Mn/64);
    int nch = (N + 1023)/1024;
    scanA<<<nch, 1024, 0, stream>>>(deg, offs, totals, N);
    scanB<<<1, 64, 0, stream>>>(totals, nch);
    fill_kernel<<<(E+255)/256, 256, 0, stream>>>(ei_raw, offs, totals, cursor, in_src, flags, E, N);

    dim3 g512(8, N/128), g1024(16, N/128);

    // GIN layer 0: gather, then triple launch {GIN-1a, v GEMM, M1}
    gather_kernel<<<(N+3)/4, 256, 0, stream>>>(Xh, Xl, offs, totals, in_src, Gh, Gl, N);
    triple_gemm<<<dim3(8, N/128, 3), 256, 0, stream>>>(
        Gh, Gl, wh_g[0], wl_g[0], gin_b1, Th, Tl,
        Xh, wh_v, wl_v, v_b, v_bf,
        sewh, sewl, wh_qk, wl_qk, zbias, M1);
    gemm_ps<1,1,3,0><<<g512, 256, 0, stream>>>(Th, Tl, wh_g[1], wl_g[1], gin_b2, Hh, Hl, nullptr, D, D);

    // GIN layers 1..2
    for (int i = 1; i < NGIN; i++){
        gather_kernel<<<(N+3)/4, 256, 0, stream>>>(Hh, Hl, offs, totals, in_src, Gh, Gl, N);
        gemm_ps<1,1,3,0><<<g512, 256, 0, stream>>>(Gh, Gl, wh_g[2*i], wl_g[2*i], gin_b1 + (size_t)i*D, Th, Tl, nullptr, D, D);
        if (i == NGIN - 1)
            gemm_ps<1,1,3,1><<<g512, 256, 0, stream>>>(Th, Tl, wh_g[2*i+1], wl_g[2*i+1], gin_b2 + (size_t)i*D, Hh, Hl, sums, D, D);
        else
            gemm_ps<1,1,3,0><<<g512, 256, 0, stream>>>(Th, Tl, wh_g[2*i+1], wl_g[2*i+1], gin_b2 + (size_t)i*D, Hh, Hl, nullptr, D, D);
    }

    // fold BN + se into qk weight
    fold_mega<<<dim3(32,16,2), 256, 0, stream>>>(M1, sums, bn_gamma, bn_beta,
        se_b, qk_w, qk_b, wbig_h, wbig_l, bbig, N);

    // qk = gin_out @ Wbig + bbig -> hi plane = pairX (N x 1024), lo plane = pairG
    gemm_ps<0,1,3,0><<<g1024, 256, 0, stream>>>(Hh, Hl, wbig_h, wbig_l, bbig, pairX, pairG, nullptr, D, 2*D);

    // attention: split qk + bf16 v -> plain bf16 output in Th
    attn_mfma_kernel<<<dim3(LMAX/128, NHEAD, B), 512, 0, stream>>>(pairX, pairG, v_bf, mbits, ptr32, Th, N);

    // out = attn_out @ out_w + out_b -> f32 d_out (2-term)
    gemm_ps<0,0,2,0><<<g512, 256, 0, stream>>>(Th, nullptr, wh_out, wl_out, out_b, (float*)d_out, nullptr, nullptr, D, D);
}